// Round 1
// baseline (2134.342 us; speedup 1.0000x reference)
//
#include <hip/hip_runtime.h>

#define NN 50000
#define NE 400000

// ---------------- degree / norm ----------------
__global__ __launch_bounds__(256) void deg_init_k(float* deg) {
    int i = blockIdx.x * 256 + threadIdx.x;
    if (i < NN) deg[i] = 1.0f;  // self-loop
}
__global__ __launch_bounds__(256) void deg_count_k(const int* __restrict__ dst, float* __restrict__ deg) {
    int e = blockIdx.x * 256 + threadIdx.x;
    if (e < NE) atomicAdd(&deg[dst[e]], 1.0f);
}
__global__ __launch_bounds__(256) void deg_fin_k(float* deg) {
    int i = blockIdx.x * 256 + threadIdx.x;
    if (i < NN) deg[i] = rsqrtf(deg[i]);  // deg >= 1 always
}

// ---------------- fp32 tiled GEMM: C = A[MxK] @ W[KxN] (+ bias) ----------------
__global__ __launch_bounds__(256) void gemm_bias_k(
    const float* __restrict__ A, const float* __restrict__ W,
    const float* __restrict__ bias, float* __restrict__ C,
    int M, int K, int N) {
    const int BM = 64, BN = 64, BK = 16;
    __shared__ float As[BK][BM];
    __shared__ float Ws[BK][BN];
    int tid = threadIdx.x;
    int tm = tid & 15;   // row group: rows tm*4 .. tm*4+3
    int tn = tid >> 4;   // col group: cols tn*4 .. tn*4+3
    int r0 = blockIdx.x * BM;
    int c0 = blockIdx.y * BN;
    float acc[4][4] = {};
    for (int k0 = 0; k0 < K; k0 += BK) {
        #pragma unroll
        for (int i = 0; i < 4; i++) {
            int l = tid + i * 256;       // 1024 elements of A tile
            int m = l >> 4;
            int kk = l & 15;
            int gr = r0 + m, gk = k0 + kk;
            As[kk][m] = (gr < M && gk < K) ? A[(size_t)gr * K + gk] : 0.0f;
        }
        #pragma unroll
        for (int i = 0; i < 4; i++) {
            int l = tid + i * 256;       // 1024 elements of W tile
            int kk = l >> 6;
            int n = l & 63;
            int gk = k0 + kk, gc = c0 + n;
            Ws[kk][n] = (gk < K && gc < N) ? W[(size_t)gk * N + gc] : 0.0f;
        }
        __syncthreads();
        #pragma unroll
        for (int kk = 0; kk < BK; kk++) {
            float a[4], b[4];
            #pragma unroll
            for (int i = 0; i < 4; i++) a[i] = As[kk][tm * 4 + i];
            #pragma unroll
            for (int j = 0; j < 4; j++) b[j] = Ws[kk][tn * 4 + j];
            #pragma unroll
            for (int i = 0; i < 4; i++)
                #pragma unroll
                for (int j = 0; j < 4; j++)
                    acc[i][j] += a[i] * b[j];
        }
        __syncthreads();
    }
    #pragma unroll
    for (int i = 0; i < 4; i++) {
        int gr = r0 + tm * 4 + i;
        if (gr >= M) continue;
        #pragma unroll
        for (int j = 0; j < 4; j++) {
            int gc = c0 + tn * 4 + j;
            if (gc >= N) continue;
            float v = acc[i][j];
            if (bias) v += bias[gc];
            C[(size_t)gr * N + gc] = v;
        }
    }
}

// ---------------- GCN aggregation ----------------
// agg[n,f] = h[n,f]*dinv[n]^2 + bias[f]   (self-loop + post-agg bias)
__global__ __launch_bounds__(256) void agg_init_k(
    const float* __restrict__ h, const float* __restrict__ dinv,
    const float* __restrict__ bias, float* __restrict__ agg, int F) {
    long i = (long)blockIdx.x * 256 + threadIdx.x;
    long total = (long)NN * F;
    if (i >= total) return;
    int n = (int)(i / F), f = (int)(i % F);
    float di = dinv[n];
    agg[i] = h[i] * di * di + bias[f];
}

// one wave per edge: agg[dst] += h[src] * dinv[src]*dinv[dst]
__global__ __launch_bounds__(256) void scatter_k(
    const int* __restrict__ src, const int* __restrict__ dst,
    const float* __restrict__ dinv, const float* __restrict__ h,
    float* __restrict__ agg, int F) {
    int gw = (blockIdx.x * 256 + threadIdx.x) >> 6;
    int lane = threadIdx.x & 63;
    if (gw >= NE) return;
    int s = src[gw], d = dst[gw];
    float nrm = dinv[s] * dinv[d];
    const float* hs = h + (size_t)s * F;
    float* ad = agg + (size_t)d * F;
    for (int f = lane; f < F; f += 64)
        atomicAdd(&ad[f], hs[f] * nrm);
}

// out = base + alpha * (relu?)(agg)
__global__ __launch_bounds__(256) void combine_k(
    const float* __restrict__ base, const float* __restrict__ agg,
    float* __restrict__ out, float alpha, int dorelu, long total) {
    long i = (long)blockIdx.x * 256 + threadIdx.x;
    if (i >= total) return;
    float a = agg[i];
    if (dorelu) a = fmaxf(a, 0.0f);
    out[i] = base[i] + alpha * a;
}

extern "C" void kernel_launch(void* const* d_in, const int* in_sizes, int n_in,
                              void* d_out, int out_size, void* d_ws, size_t ws_size,
                              hipStream_t stream) {
    const float* x   = (const float*)d_in[0];
    const int*   ei  = (const int*)d_in[1];
    const float* W1  = (const float*)d_in[2];  const float* b1  = (const float*)d_in[3];
    const float* W2  = (const float*)d_in[4];  const float* b2  = (const float*)d_in[5];
    const float* W3  = (const float*)d_in[6];  const float* b3  = (const float*)d_in[7];
    const float* Wg1 = (const float*)d_in[8];  const float* bg1 = (const float*)d_in[9];
    const float* Wg2 = (const float*)d_in[10]; const float* bg2 = (const float*)d_in[11];
    const float* Wg3 = (const float*)d_in[12]; const float* bg3 = (const float*)d_in[13];
    const float* Wg4 = (const float*)d_in[14]; const float* bg4 = (const float*)d_in[15];
    const float* Wg5 = (const float*)d_in[16]; const float* bg5 = (const float*)d_in[17];
    const float* Wg6 = (const float*)d_in[18]; const float* bg6 = (const float*)d_in[19];
    const int* srcv = ei;
    const int* dstv = ei + NE;

    float* dinv = (float*)d_ws;                 // N (padded to 51200)
    float* A = dinv + 51200;                    // N x 256
    float* B = A + (size_t)NN * 256;            // N x 256
    float* C = B + (size_t)NN * 256;            // N x 256

    // degrees -> dinv
    deg_init_k<<<(NN + 255) / 256, 256, 0, stream>>>(dinv);
    deg_count_k<<<(NE + 255) / 256, 256, 0, stream>>>(dstv, dinv);
    deg_fin_k<<<(NN + 255) / 256, 256, 0, stream>>>(dinv);

    auto gemm = [&](const float* Ain, const float* W, const float* bias, float* Cout,
                    int M, int K, int Nn) {
        dim3 grid((M + 63) / 64, (Nn + 63) / 64);
        gemm_bias_k<<<grid, 256, 0, stream>>>(Ain, W, bias, Cout, M, K, Nn);
    };
    auto gcn_agg = [&](const float* h, const float* bias, float* agg, int F) {
        long total = (long)NN * F;
        agg_init_k<<<(int)((total + 255) / 256), 256, 0, stream>>>(h, dinv, bias, agg, F);
        scatter_k<<<(NE * 64 + 255) / 256, 256, 0, stream>>>(srcv, dstv, dinv, h, agg, F);
    };
    auto combine = [&](const float* base, const float* agg, float* out, float alpha, int relu, int F) {
        long total = (long)NN * F;
        combine_k<<<(int)((total + 255) / 256), 256, 0, stream>>>(base, agg, out, alpha, relu, total);
    };

    // L1: x1l = x@W1+b1 -> A ; x1 = x1l + relu(gcn(x1l,Wg1,bg1)) -> B
    gemm(x, W1, b1, A, NN, 512, 256);
    gemm(A, Wg1, nullptr, B, NN, 256, 256);
    gcn_agg(B, bg1, C, 256);
    combine(A, C, B, 1.0f, 1, 256);
    // L2: x2l -> A ; x2 -> B
    gemm(B, W2, b2, A, NN, 256, 62);
    gemm(A, Wg2, nullptr, B, NN, 62, 62);
    gcn_agg(B, bg2, C, 62);
    combine(A, C, B, 1.0f, 1, 62);
    // L3: x3l -> A ; x3 = x3l + 0.5*relu(gcn) -> B
    gemm(B, W3, b3, A, NN, 62, 128);
    gemm(A, Wg3, nullptr, B, NN, 128, 128);
    gcn_agg(B, bg3, C, 128);
    combine(A, C, B, 0.5f, 1, 128);
    // L4: x4 = x3 + 0.5*relu(gcn(x3,Wg4,bg4)) -> B (in place)
    gemm(B, Wg4, nullptr, A, NN, 128, 128);
    gcn_agg(A, bg4, C, 128);
    combine(B, C, B, 0.5f, 1, 128);
    // L5: x5 = x4 + 0.25*relu(gcn(x4,Wg5,bg5)) -> B
    gemm(B, Wg5, nullptr, A, NN, 128, 128);
    gcn_agg(A, bg5, C, 128);
    combine(B, C, B, 0.25f, 1, 128);
    // L6: x6 = x5 + 0.25*gcn(x5,Wg6,bg6) -> d_out (no relu)
    gemm(B, Wg6, nullptr, A, NN, 128, 128);
    gcn_agg(A, bg6, C, 128);
    combine(B, C, (float*)d_out, 0.25f, 0, 128);
}

// Round 2
// 1547.816 us; speedup vs baseline: 1.3789x; 1.3789x over previous
//
#include <hip/hip_runtime.h>

#define NN 50000
#define NE 400000

using short8 = __attribute__((ext_vector_type(8))) short;
using f32x4  = __attribute__((ext_vector_type(4))) float;

__device__ __forceinline__ unsigned short f2b(float f) {
    union { float f; unsigned int u; } x; x.f = f;
    unsigned int u = x.u;
    u += 0x7fffu + ((u >> 16) & 1u);   // round-to-nearest-even
    return (unsigned short)(u >> 16);
}

#define SWZ(b, row) ((b) ^ (((row) & 7) << 4))

// ---------------- degree / norm ----------------
__global__ __launch_bounds__(256) void deg_init_k(float* deg) {
    int i = blockIdx.x * 256 + threadIdx.x;
    if (i < NN) deg[i] = 1.0f;  // self-loop
}
__global__ __launch_bounds__(256) void deg_count_k(const int* __restrict__ dst, float* __restrict__ deg) {
    int e = blockIdx.x * 256 + threadIdx.x;
    if (e < NE) unsafeAtomicAdd(&deg[dst[e]], 1.0f);
}
__global__ __launch_bounds__(256) void deg_fin_k(float* deg) {
    int i = blockIdx.x * 256 + threadIdx.x;
    if (i < NN) deg[i] = rsqrtf(deg[i]);
}

// ---------------- weight cast+transpose: Wt[n][k] = bf16(W[k][n]), zero-padded ----------------
__global__ __launch_bounds__(256) void wcast_k(const float* __restrict__ W, unsigned short* __restrict__ Wt,
                                               int K, int N, int Kp, int Np) {
    int idx = blockIdx.x * 256 + threadIdx.x;
    if (idx >= Kp * Np) return;
    int n = idx / Kp, k = idx % Kp;
    float v = (n < N && k < K) ? W[(size_t)k * N + n] : 0.0f;
    Wt[idx] = f2b(v);
}

// ---------------- MFMA bf16 GEMM: C[M x N] = A[M x Kp](fp32) @ Wt[Np x Kp]^T, + bias ----------
// Tile: BM=128, BN=64, BK=64. 4 waves, each computes 64x32 (4x2 frags of 16x16).
__global__ __launch_bounds__(256) void gemm_mfma_k(
    const float* __restrict__ A, const unsigned short* __restrict__ Bt,
    const float* __restrict__ bias, float* __restrict__ C,
    int M, int lda, int Kp, int N, int ldc) {
    __shared__ char lds[24576];          // As: 128x64 bf16 (16KB) + Bs: 64x64 bf16 (8KB)
    char* AsB = lds;
    char* BsB = lds + 16384;

    int tid  = threadIdx.x;
    int lane = tid & 63;
    int wave = tid >> 6;
    int wr = wave >> 1, wc = wave & 1;
    int lr = lane & 15, lk = lane >> 4;          // frag row/col, k-octet
    int r0 = blockIdx.x * 128;
    int c0 = blockIdx.y * 64;

    f32x4 acc[4][2];
    #pragma unroll
    for (int m = 0; m < 4; m++)
        #pragma unroll
        for (int n = 0; n < 2; n++)
            acc[m][n] = (f32x4){0.f, 0.f, 0.f, 0.f};

    for (int k0 = 0; k0 < Kp; k0 += 64) {
        // stage A tile (fp32 -> bf16), 128 rows x 64 cols = 1024 octets
        #pragma unroll
        for (int c = 0; c < 4; c++) {
            int o = tid + c * 256;
            int row = o >> 3, oct = o & 7;
            int gr = r0 + row;
            float4 f0, f1;
            if (gr < M) {
                const float* p = A + (size_t)gr * lda + k0 + oct * 8;
                f0 = *(const float4*)p;
                f1 = *(const float4*)(p + 4);
            } else {
                f0 = make_float4(0, 0, 0, 0);
                f1 = make_float4(0, 0, 0, 0);
            }
            short8 v;
            v[0] = (short)f2b(f0.x); v[1] = (short)f2b(f0.y);
            v[2] = (short)f2b(f0.z); v[3] = (short)f2b(f0.w);
            v[4] = (short)f2b(f1.x); v[5] = (short)f2b(f1.y);
            v[6] = (short)f2b(f1.z); v[7] = (short)f2b(f1.w);
            *(short8*)(AsB + SWZ(row * 128 + oct * 16, row)) = v;
        }
        // stage B tile (bf16, pre-transposed): 64 rows(n) x 64 cols(k) = 512 octets
        #pragma unroll
        for (int c = 0; c < 2; c++) {
            int o = tid + c * 256;
            int row = o >> 3, oct = o & 7;
            short8 v = *(const short8*)(Bt + (size_t)(c0 + row) * Kp + k0 + oct * 8);
            *(short8*)(BsB + SWZ(row * 128 + oct * 16, row)) = v;
        }
        __syncthreads();
        #pragma unroll
        for (int kk = 0; kk < 2; kk++) {
            int kb = kk * 64 + lk * 16;   // byte offset of this lane's k-octet
            short8 a[4], b[2];
            #pragma unroll
            for (int m = 0; m < 4; m++) {
                int row = wr * 64 + m * 16 + lr;
                a[m] = *(short8*)(AsB + SWZ(row * 128 + kb, row));
            }
            #pragma unroll
            for (int n = 0; n < 2; n++) {
                int row = wc * 32 + n * 16 + lr;
                b[n] = *(short8*)(BsB + SWZ(row * 128 + kb, row));
            }
            #pragma unroll
            for (int m = 0; m < 4; m++)
                #pragma unroll
                for (int n = 0; n < 2; n++)
                    acc[m][n] = __builtin_amdgcn_mfma_f32_16x16x32_bf16(a[m], b[n], acc[m][n], 0, 0, 0);
        }
        __syncthreads();
    }
    // epilogue: C/D layout col=lane&15, row=(lane>>4)*4+j
    #pragma unroll
    for (int n = 0; n < 2; n++) {
        int gc = c0 + wc * 32 + n * 16 + lr;
        float bv = (bias && gc < N) ? bias[gc] : 0.0f;
        #pragma unroll
        for (int m = 0; m < 4; m++) {
            #pragma unroll
            for (int j = 0; j < 4; j++) {
                int gr = r0 + wr * 64 + m * 16 + lk * 4 + j;
                if (gr < M) {
                    float v = (gc < N) ? acc[m][n][j] + bv : 0.0f;
                    C[(size_t)gr * ldc + gc] = v;
                }
            }
        }
    }
}

// ---------------- GCN aggregation ----------------
// agg[n,f] = h[n,f]*dinv[n]^2 + bias[f] for f<F, 0 for pad cols
__global__ __launch_bounds__(256) void agg_init_k(
    const float* __restrict__ h, const float* __restrict__ dinv,
    const float* __restrict__ bias, float* __restrict__ agg, int F, int ld) {
    long i = (long)blockIdx.x * 256 + threadIdx.x;
    long total = (long)NN * ld;
    if (i >= total) return;
    int n = (int)(i / ld), f = (int)(i % ld);
    float di = dinv[n];
    agg[i] = (f < F) ? h[i] * di * di + bias[f] : 0.0f;
}

// one wave per edge: agg[dst] += h[src] * dinv[src]*dinv[dst]
__global__ __launch_bounds__(256) void scatter_k(
    const int* __restrict__ src, const int* __restrict__ dst,
    const float* __restrict__ dinv, const float* __restrict__ h,
    float* __restrict__ agg, int F, int ld) {
    int gw = (blockIdx.x * 256 + threadIdx.x) >> 6;
    int lane = threadIdx.x & 63;
    if (gw >= NE) return;
    int s = src[gw], d = dst[gw];
    float nrm = dinv[s] * dinv[d];
    const float* hs = h + (size_t)s * ld;
    float* ad = agg + (size_t)d * ld;
    for (int f = lane; f < F; f += 64)
        unsafeAtomicAdd(&ad[f], hs[f] * nrm);
}

// out = base + alpha * (relu?)(agg); pad cols -> 0
__global__ __launch_bounds__(256) void combine_k(
    const float* __restrict__ base, const float* __restrict__ agg,
    float* __restrict__ out, float alpha, int dorelu, int F, int ld) {
    long i = (long)blockIdx.x * 256 + threadIdx.x;
    long total = (long)NN * ld;
    if (i >= total) return;
    int f = (int)(i % ld);
    float a = agg[i];
    if (dorelu) a = fmaxf(a, 0.0f);
    out[i] = (f < F) ? base[i] + alpha * a : 0.0f;
}

extern "C" void kernel_launch(void* const* d_in, const int* in_sizes, int n_in,
                              void* d_out, int out_size, void* d_ws, size_t ws_size,
                              hipStream_t stream) {
    const float* x   = (const float*)d_in[0];
    const int*   ei  = (const int*)d_in[1];
    const float* W1  = (const float*)d_in[2];  const float* b1  = (const float*)d_in[3];
    const float* W2  = (const float*)d_in[4];  const float* b2  = (const float*)d_in[5];
    const float* W3  = (const float*)d_in[6];  const float* b3  = (const float*)d_in[7];
    const float* Wg1 = (const float*)d_in[8];  const float* bg1 = (const float*)d_in[9];
    const float* Wg2 = (const float*)d_in[10]; const float* bg2 = (const float*)d_in[11];
    const float* Wg3 = (const float*)d_in[12]; const float* bg3 = (const float*)d_in[13];
    const float* Wg4 = (const float*)d_in[14]; const float* bg4 = (const float*)d_in[15];
    const float* Wg5 = (const float*)d_in[16]; const float* bg5 = (const float*)d_in[17];
    const float* Wg6 = (const float*)d_in[18]; const float* bg6 = (const float*)d_in[19];
    const int* srcv = ei;
    const int* dstv = ei + NE;

    float* dinv = (float*)d_ws;                      // 51200 floats
    float* A = dinv + 51200;                         // N x 256 fp32
    float* B = A + (size_t)NN * 256;
    float* C = B + (size_t)NN * 256;
    unsigned short* wt = (unsigned short*)(C + (size_t)NN * 256);
    unsigned short* W1t  = wt;               // 256 x 512
    unsigned short* Wg1t = W1t  + 256 * 512; // 256 x 256
    unsigned short* W2t  = Wg1t + 256 * 256; // 64  x 256
    unsigned short* Wg2t = W2t  + 64 * 256;  // 64  x 64
    unsigned short* W3t  = Wg2t + 64 * 64;   // 128 x 64
    unsigned short* Wg3t = W3t  + 128 * 64;  // 128 x 128
    unsigned short* Wg4t = Wg3t + 128 * 128;
    unsigned short* Wg5t = Wg4t + 128 * 128;
    unsigned short* Wg6t = Wg5t + 128 * 128;

    auto wcast = [&](const float* W, unsigned short* Wt, int K, int N, int Kp, int Np) {
        wcast_k<<<(Kp * Np + 255) / 256, 256, 0, stream>>>(W, Wt, K, N, Kp, Np);
    };
    wcast(W1,  W1t,  512, 256, 512, 256);
    wcast(Wg1, Wg1t, 256, 256, 256, 256);
    wcast(W2,  W2t,  256,  62, 256,  64);
    wcast(Wg2, Wg2t,  62,  62,  64,  64);
    wcast(W3,  W3t,   62, 128,  64, 128);
    wcast(Wg3, Wg3t, 128, 128, 128, 128);
    wcast(Wg4, Wg4t, 128, 128, 128, 128);
    wcast(Wg5, Wg5t, 128, 128, 128, 128);
    wcast(Wg6, Wg6t, 128, 128, 128, 128);

    deg_init_k<<<(NN + 255) / 256, 256, 0, stream>>>(dinv);
    deg_count_k<<<(NE + 255) / 256, 256, 0, stream>>>(dstv, dinv);
    deg_fin_k<<<(NN + 255) / 256, 256, 0, stream>>>(dinv);

    auto gemm = [&](const float* Ain, int lda, int Kp, const unsigned short* Bt,
                    const float* bias, float* Cout, int N, int ldc) {
        dim3 grid((NN + 127) / 128, ldc / 64);
        gemm_mfma_k<<<grid, 256, 0, stream>>>(Ain, Bt, bias, Cout, NN, lda, Kp, N, ldc);
    };
    auto gcn_agg = [&](const float* h, const float* bias, float* agg, int F, int ld) {
        long total = (long)NN * ld;
        agg_init_k<<<(int)((total + 255) / 256), 256, 0, stream>>>(h, dinv, bias, agg, F, ld);
        scatter_k<<<(NE * 64 + 255) / 256, 256, 0, stream>>>(srcv, dstv, dinv, h, agg, F, ld);
    };
    auto combine = [&](const float* base, const float* agg, float* out, float alpha, int relu, int F, int ld) {
        long total = (long)NN * ld;
        combine_k<<<(int)((total + 255) / 256), 256, 0, stream>>>(base, agg, out, alpha, relu, F, ld);
    };

    // L1: x1l -> A ; x1 -> B
    gemm(x, 512, 512, W1t, b1, A, 256, 256);
    gemm(A, 256, 256, Wg1t, nullptr, B, 256, 256);
    gcn_agg(B, bg1, C, 256, 256);
    combine(A, C, B, 1.0f, 1, 256, 256);
    // L2: x2l -> A (ld 64) ; x2 -> B (ld 64)
    gemm(B, 256, 256, W2t, b2, A, 62, 64);
    gemm(A, 64, 64, Wg2t, nullptr, B, 62, 64);
    gcn_agg(B, bg2, C, 62, 64);
    combine(A, C, B, 1.0f, 1, 62, 64);
    // L3: x3l -> A ; x3 -> B
    gemm(B, 64, 64, W3t, b3, A, 128, 128);
    gemm(A, 128, 128, Wg3t, nullptr, B, 128, 128);
    gcn_agg(B, bg3, C, 128, 128);
    combine(A, C, B, 0.5f, 1, 128, 128);
    // L4
    gemm(B, 128, 128, Wg4t, nullptr, A, 128, 128);
    gcn_agg(A, bg4, C, 128, 128);
    combine(B, C, B, 0.5f, 1, 128, 128);
    // L5
    gemm(B, 128, 128, Wg5t, nullptr, A, 128, 128);
    gcn_agg(A, bg5, C, 128, 128);
    combine(B, C, B, 0.25f, 1, 128, 128);
    // L6 -> d_out
    gemm(B, 128, 128, Wg6t, nullptr, A, 128, 128);
    gcn_agg(A, bg6, C, 128, 128);
    combine(B, C, (float*)d_out, 0.25f, 0, 128, 128);
}

// Round 3
// 647.194 us; speedup vs baseline: 3.2978x; 2.3916x over previous
//
#include <hip/hip_runtime.h>

#define NN 50000
#define NE 400000
#define NBLK 196   // ceil(NN/256)

using short8 = __attribute__((ext_vector_type(8))) short;
using f32x4  = __attribute__((ext_vector_type(4))) float;

__device__ __forceinline__ unsigned short f2b(float f) {
    union { float f; unsigned int u; } x; x.f = f;
    unsigned int u = x.u;
    u += 0x7fffu + ((u >> 16) & 1u);   // round-to-nearest-even
    return (unsigned short)(u >> 16);
}

#define SWZ(b, row) ((b) ^ (((row) & 7) << 4))

// ---------------- CSR build ----------------
__global__ __launch_bounds__(256) void zero2_k(int* a, int* b) {
    int i = blockIdx.x * 256 + threadIdx.x;
    if (i < NN) { a[i] = 0; b[i] = 0; }
}
__global__ __launch_bounds__(256) void count_k(const int* __restrict__ dst, int* __restrict__ indeg) {
    int e = blockIdx.x * 256 + threadIdx.x;
    if (e < NE) atomicAdd(&indeg[dst[e]], 1);
}
__global__ __launch_bounds__(256) void dinv_k(const int* __restrict__ indeg, float* __restrict__ dinv) {
    int i = blockIdx.x * 256 + threadIdx.x;
    if (i < NN) dinv[i] = rsqrtf((float)(1 + indeg[i]));
}
__global__ __launch_bounds__(256) void scan1_k(const int* __restrict__ indeg, int* __restrict__ tmp,
                                               int* __restrict__ bsum) {
    __shared__ int s[256];
    int t = threadIdx.x, i = blockIdx.x * 256 + t;
    int v = (i < NN) ? indeg[i] : 0;
    s[t] = v; __syncthreads();
    for (int off = 1; off < 256; off <<= 1) {
        int x = (t >= off) ? s[t - off] : 0;
        __syncthreads();
        s[t] += x;
        __syncthreads();
    }
    if (i < NN) tmp[i] = s[t];
    if (t == 255) bsum[blockIdx.x] = s[255];
}
__global__ __launch_bounds__(256) void scan2_k(const int* __restrict__ bsum, int* __restrict__ boff) {
    __shared__ int s[256];
    int t = threadIdx.x;
    int v = (t < NBLK) ? bsum[t] : 0;
    s[t] = v; __syncthreads();
    for (int off = 1; off < 256; off <<= 1) {
        int x = (t >= off) ? s[t - off] : 0;
        __syncthreads();
        s[t] += x;
        __syncthreads();
    }
    if (t < NBLK) boff[t] = s[t] - v;   // exclusive
}
__global__ __launch_bounds__(256) void scan3_k(const int* __restrict__ tmp, const int* __restrict__ indeg,
                                               const int* __restrict__ boff, int* __restrict__ rowptr) {
    int i = blockIdx.x * 256 + threadIdx.x;
    if (i < NN) rowptr[i] = tmp[i] - indeg[i] + boff[i >> 8];
    if (i == 0) rowptr[NN] = NE;
}
__global__ __launch_bounds__(256) void fill_k(const int* __restrict__ src, const int* __restrict__ dst,
                                              const float* __restrict__ dinv, const int* __restrict__ rowptr,
                                              int* __restrict__ cursor, int* __restrict__ ebuf,
                                              float* __restrict__ nbuf) {
    int e = blockIdx.x * 256 + threadIdx.x;
    if (e >= NE) return;
    int s = src[e], d = dst[e];
    int pos = atomicAdd(&cursor[d], 1);
    int idx = rowptr[d] + pos;
    ebuf[idx] = s;
    nbuf[idx] = dinv[s] * dinv[d];
}

// ---------------- weight cast+transpose ----------------
__global__ __launch_bounds__(256) void wcast_k(const float* __restrict__ W, unsigned short* __restrict__ Wt,
                                               int K, int N, int Kp, int Np) {
    int idx = blockIdx.x * 256 + threadIdx.x;
    if (idx >= Kp * Np) return;
    int n = idx / Kp, k = idx % Kp;
    float v = (n < N && k < K) ? W[(size_t)k * N + n] : 0.0f;
    Wt[idx] = f2b(v);
}

// ---------------- MFMA bf16 GEMM: C[M x N] = A[M x Kp](fp32) @ Wt[Np x Kp]^T, + bias ----------
__global__ __launch_bounds__(256) void gemm_mfma_k(
    const float* __restrict__ A, const unsigned short* __restrict__ Bt,
    const float* __restrict__ bias, float* __restrict__ C,
    int M, int lda, int Kp, int N, int ldc) {
    __shared__ char lds[24576];
    char* AsB = lds;
    char* BsB = lds + 16384;

    int tid  = threadIdx.x;
    int lane = tid & 63;
    int wave = tid >> 6;
    int wr = wave >> 1, wc = wave & 1;
    int lr = lane & 15, lk = lane >> 4;
    int r0 = blockIdx.x * 128;
    int c0 = blockIdx.y * 64;

    f32x4 acc[4][2];
    #pragma unroll
    for (int m = 0; m < 4; m++)
        #pragma unroll
        for (int n = 0; n < 2; n++)
            acc[m][n] = (f32x4){0.f, 0.f, 0.f, 0.f};

    for (int k0 = 0; k0 < Kp; k0 += 64) {
        #pragma unroll
        for (int c = 0; c < 4; c++) {
            int o = tid + c * 256;
            int row = o >> 3, oct = o & 7;
            int gr = r0 + row;
            float4 f0, f1;
            if (gr < M) {
                const float* p = A + (size_t)gr * lda + k0 + oct * 8;
                f0 = *(const float4*)p;
                f1 = *(const float4*)(p + 4);
            } else {
                f0 = make_float4(0, 0, 0, 0);
                f1 = make_float4(0, 0, 0, 0);
            }
            short8 v;
            v[0] = (short)f2b(f0.x); v[1] = (short)f2b(f0.y);
            v[2] = (short)f2b(f0.z); v[3] = (short)f2b(f0.w);
            v[4] = (short)f2b(f1.x); v[5] = (short)f2b(f1.y);
            v[6] = (short)f2b(f1.z); v[7] = (short)f2b(f1.w);
            *(short8*)(AsB + SWZ(row * 128 + oct * 16, row)) = v;
        }
        #pragma unroll
        for (int c = 0; c < 2; c++) {
            int o = tid + c * 256;
            int row = o >> 3, oct = o & 7;
            short8 v = *(const short8*)(Bt + (size_t)(c0 + row) * Kp + k0 + oct * 8);
            *(short8*)(BsB + SWZ(row * 128 + oct * 16, row)) = v;
        }
        __syncthreads();
        #pragma unroll
        for (int kk = 0; kk < 2; kk++) {
            int kb = kk * 64 + lk * 16;
            short8 a[4], b[2];
            #pragma unroll
            for (int m = 0; m < 4; m++) {
                int row = wr * 64 + m * 16 + lr;
                a[m] = *(short8*)(AsB + SWZ(row * 128 + kb, row));
            }
            #pragma unroll
            for (int n = 0; n < 2; n++) {
                int row = wc * 32 + n * 16 + lr;
                b[n] = *(short8*)(BsB + SWZ(row * 128 + kb, row));
            }
            #pragma unroll
            for (int m = 0; m < 4; m++)
                #pragma unroll
                for (int n = 0; n < 2; n++)
                    acc[m][n] = __builtin_amdgcn_mfma_f32_16x16x32_bf16(a[m], b[n], acc[m][n], 0, 0, 0);
        }
        __syncthreads();
    }
    #pragma unroll
    for (int n = 0; n < 2; n++) {
        int gc = c0 + wc * 32 + n * 16 + lr;
        float bv = (bias && gc < N) ? bias[gc] : 0.0f;
        #pragma unroll
        for (int m = 0; m < 4; m++) {
            #pragma unroll
            for (int j = 0; j < 4; j++) {
                int gr = r0 + wr * 64 + m * 16 + lk * 4 + j;
                if (gr < M) {
                    float v = (gc < N) ? acc[m][n][j] + bv : 0.0f;
                    C[(size_t)gr * ldc + gc] = v;
                }
            }
        }
    }
}

// ---------------- fused GCN aggregate + combine (CSR gather) ----------------
template<int VEC> struct VecT;
template<> struct VecT<1> { using T = float;  };
template<> struct VecT<2> { using T = float2; };
template<> struct VecT<4> { using T = float4; };

// out[n] = base[n] + alpha * maybe_relu( sum_{e in csr[n]} norm_e * h[src_e] + h[n]*dinv[n]^2 + bias )
template<int VEC>
__global__ __launch_bounds__(256) void gather_k(
    const float* __restrict__ h, const float* __restrict__ base,
    const float* __restrict__ dinv, const float* __restrict__ bias,
    const int* __restrict__ ebuf, const float* __restrict__ nbuf,
    const int* __restrict__ rowptr, float* __restrict__ out,
    float alpha, int dorelu, int F) {
    const int ld = 64 * VEC;
    int w = (blockIdx.x * 256 + threadIdx.x) >> 6;
    int lane = threadIdx.x & 63;
    if (w >= NN) return;
    using LT = typename VecT<VEC>::T;

    float acc[VEC];
    float dn = dinv[w];
    {
        LT t = *(const LT*)(h + (size_t)w * ld + lane * VEC);
        const float* tf = (const float*)&t;
        #pragma unroll
        for (int v = 0; v < VEC; v++) acc[v] = tf[v] * dn * dn;
    }
    int e = rowptr[w], end = rowptr[w + 1];
    for (; e < end; e++) {
        int s = ebuf[e];
        float nr = nbuf[e];
        LT t = *(const LT*)(h + (size_t)s * ld + lane * VEC);
        const float* tf = (const float*)&t;
        #pragma unroll
        for (int v = 0; v < VEC; v++) acc[v] += tf[v] * nr;
    }
    LT bt = *(const LT*)(base + (size_t)w * ld + lane * VEC);
    const float* bf = (const float*)&bt;
    LT ot;
    float* of = (float*)&ot;
    #pragma unroll
    for (int v = 0; v < VEC; v++) {
        int f = lane * VEC + v;
        float a = acc[v] + ((f < F) ? bias[f] : 0.0f);
        if (dorelu) a = fmaxf(a, 0.0f);
        of[v] = (f < F) ? bf[v] + alpha * a : 0.0f;
    }
    *(LT*)(out + (size_t)w * ld + lane * VEC) = ot;
}

extern "C" void kernel_launch(void* const* d_in, const int* in_sizes, int n_in,
                              void* d_out, int out_size, void* d_ws, size_t ws_size,
                              hipStream_t stream) {
    const float* x   = (const float*)d_in[0];
    const int*   ei  = (const int*)d_in[1];
    const float* W1  = (const float*)d_in[2];  const float* b1  = (const float*)d_in[3];
    const float* W2  = (const float*)d_in[4];  const float* b2  = (const float*)d_in[5];
    const float* W3  = (const float*)d_in[6];  const float* b3  = (const float*)d_in[7];
    const float* Wg1 = (const float*)d_in[8];  const float* bg1 = (const float*)d_in[9];
    const float* Wg2 = (const float*)d_in[10]; const float* bg2 = (const float*)d_in[11];
    const float* Wg3 = (const float*)d_in[12]; const float* bg3 = (const float*)d_in[13];
    const float* Wg4 = (const float*)d_in[14]; const float* bg4 = (const float*)d_in[15];
    const float* Wg5 = (const float*)d_in[16]; const float* bg5 = (const float*)d_in[17];
    const float* Wg6 = (const float*)d_in[18]; const float* bg6 = (const float*)d_in[19];
    const int* srcv = ei;
    const int* dstv = ei + NE;

    float* dinv = (float*)d_ws;                      // 51200
    float* A = dinv + 51200;                         // N x 256
    float* B = A + (size_t)NN * 256;
    float* C = B + (size_t)NN * 256;
    unsigned short* wt = (unsigned short*)(C + (size_t)NN * 256);
    unsigned short* W1t  = wt;               // 256 x 512
    unsigned short* Wg1t = W1t  + 256 * 512;
    unsigned short* W2t  = Wg1t + 256 * 256;
    unsigned short* Wg2t = W2t  + 64 * 256;
    unsigned short* W3t  = Wg2t + 64 * 64;
    unsigned short* Wg3t = W3t  + 128 * 64;
    unsigned short* Wg4t = Wg3t + 128 * 128;
    unsigned short* Wg5t = Wg4t + 128 * 128;
    unsigned short* Wg6t = Wg5t + 128 * 128;
    int* indeg  = (int*)(Wg6t + 128 * 128 + 128);   // 51200 (pad to even)
    int* cursor = indeg + 51200;
    int* tmp    = cursor + 51200;
    int* rowptr = tmp + 51200;                       // 51264
    int* bsum   = rowptr + 51264;
    int* boff   = bsum + 256;
    int* ebuf   = boff + 256;                        // 400000
    float* nbuf = (float*)(ebuf + 400000);           // 400000

    // CSR + dinv
    zero2_k<<<NBLK, 256, 0, stream>>>(indeg, cursor);
    count_k<<<(NE + 255) / 256, 256, 0, stream>>>(dstv, indeg);
    dinv_k<<<NBLK, 256, 0, stream>>>(indeg, dinv);
    scan1_k<<<NBLK, 256, 0, stream>>>(indeg, tmp, bsum);
    scan2_k<<<1, 256, 0, stream>>>(bsum, boff);
    scan3_k<<<NBLK, 256, 0, stream>>>(tmp, indeg, boff, rowptr);
    fill_k<<<(NE + 255) / 256, 256, 0, stream>>>(srcv, dstv, dinv, rowptr, cursor, ebuf, nbuf);

    auto wcast = [&](const float* W, unsigned short* Wt, int K, int N, int Kp, int Np) {
        wcast_k<<<(Kp * Np + 255) / 256, 256, 0, stream>>>(W, Wt, K, N, Kp, Np);
    };
    wcast(W1,  W1t,  512, 256, 512, 256);
    wcast(Wg1, Wg1t, 256, 256, 256, 256);
    wcast(W2,  W2t,  256,  62, 256,  64);
    wcast(Wg2, Wg2t,  62,  62,  64,  64);
    wcast(W3,  W3t,   62, 128,  64, 128);
    wcast(Wg3, Wg3t, 128, 128, 128, 128);
    wcast(Wg4, Wg4t, 128, 128, 128, 128);
    wcast(Wg5, Wg5t, 128, 128, 128, 128);
    wcast(Wg6, Wg6t, 128, 128, 128, 128);

    auto gemm = [&](const float* Ain, int lda, int Kp, const unsigned short* Bt,
                    const float* bias, float* Cout, int N, int ldc) {
        dim3 grid((NN + 127) / 128, ldc / 64);
        gemm_mfma_k<<<grid, 256, 0, stream>>>(Ain, Bt, bias, Cout, NN, lda, Kp, N, ldc);
    };
    const int GG = (NN * 64 + 255) / 256;   // one wave per node

    // L1: x1l -> A ; h -> B ; x1 -> C
    gemm(x, 512, 512, W1t, b1, A, 256, 256);
    gemm(A, 256, 256, Wg1t, nullptr, B, 256, 256);
    gather_k<4><<<GG, 256, 0, stream>>>(B, A, dinv, bg1, ebuf, nbuf, rowptr, C, 1.0f, 1, 256);
    // L2: x2l -> A ; h -> B ; x2 -> C (ld 64)
    gemm(C, 256, 256, W2t, b2, A, 62, 64);
    gemm(A, 64, 64, Wg2t, nullptr, B, 62, 64);
    gather_k<1><<<GG, 256, 0, stream>>>(B, A, dinv, bg2, ebuf, nbuf, rowptr, C, 1.0f, 1, 62);
    // L3: x3l -> A ; h -> B ; x3 -> C (ld 128)
    gemm(C, 64, 64, W3t, b3, A, 128, 128);
    gemm(A, 128, 128, Wg3t, nullptr, B, 128, 128);
    gather_k<2><<<GG, 256, 0, stream>>>(B, A, dinv, bg3, ebuf, nbuf, rowptr, C, 0.5f, 1, 128);
    // L4: h -> A ; x4 -> B
    gemm(C, 128, 128, Wg4t, nullptr, A, 128, 128);
    gather_k<2><<<GG, 256, 0, stream>>>(A, C, dinv, bg4, ebuf, nbuf, rowptr, B, 0.5f, 1, 128);
    // L5: h -> A ; x5 -> C
    gemm(B, 128, 128, Wg5t, nullptr, A, 128, 128);
    gather_k<2><<<GG, 256, 0, stream>>>(A, B, dinv, bg5, ebuf, nbuf, rowptr, C, 0.25f, 1, 128);
    // L6: h -> A ; x6 -> d_out
    gemm(C, 128, 128, Wg6t, nullptr, A, 128, 128);
    gather_k<2><<<GG, 256, 0, stream>>>(A, C, dinv, bg6, ebuf, nbuf, rowptr, (float*)d_out, 0.25f, 0, 128);
}

// Round 4
// 501.735 us; speedup vs baseline: 4.2539x; 1.2899x over previous
//
#include <hip/hip_runtime.h>

#define NN 50000
#define NE 400000
#define NBLK 196   // ceil(NN/256)

using short8 = __attribute__((ext_vector_type(8))) short;
using f32x4  = __attribute__((ext_vector_type(4))) float;
using u16x2  = __attribute__((ext_vector_type(2))) unsigned short;
using u16x4  = __attribute__((ext_vector_type(4))) unsigned short;

__device__ __forceinline__ unsigned short f2b(float f) {
    union { float f; unsigned int u; } x; x.f = f;
    unsigned int u = x.u;
    u += 0x7fffu + ((u >> 16) & 1u);   // RNE
    return (unsigned short)(u >> 16);
}
__device__ __forceinline__ float b2f(unsigned short u) {
    union { unsigned int u; float f; } x; x.u = ((unsigned int)u) << 16;
    return x.f;
}

#define SWZ(b, row) ((b) ^ (((row) & 7) << 4))

// ---------------- CSR build ----------------
__global__ __launch_bounds__(256) void zero2_k(int* a, int* b) {
    int i = blockIdx.x * 256 + threadIdx.x;
    if (i < NN) { a[i] = 0; b[i] = 0; }
}
__global__ __launch_bounds__(256) void count_k(const int* __restrict__ dst, int* __restrict__ indeg) {
    int e = blockIdx.x * 256 + threadIdx.x;
    if (e < NE) atomicAdd(&indeg[dst[e]], 1);
}
__global__ __launch_bounds__(256) void dinv_k(const int* __restrict__ indeg, float* __restrict__ dinv) {
    int i = blockIdx.x * 256 + threadIdx.x;
    if (i < NN) dinv[i] = rsqrtf((float)(1 + indeg[i]));
}
__global__ __launch_bounds__(256) void scan1_k(const int* __restrict__ indeg, int* __restrict__ tmp,
                                               int* __restrict__ bsum) {
    __shared__ int s[256];
    int t = threadIdx.x, i = blockIdx.x * 256 + t;
    int v = (i < NN) ? indeg[i] : 0;
    s[t] = v; __syncthreads();
    for (int off = 1; off < 256; off <<= 1) {
        int x = (t >= off) ? s[t - off] : 0;
        __syncthreads();
        s[t] += x;
        __syncthreads();
    }
    if (i < NN) tmp[i] = s[t];
    if (t == 255) bsum[blockIdx.x] = s[255];
}
__global__ __launch_bounds__(256) void scan2_k(const int* __restrict__ bsum, int* __restrict__ boff) {
    __shared__ int s[256];
    int t = threadIdx.x;
    int v = (t < NBLK) ? bsum[t] : 0;
    s[t] = v; __syncthreads();
    for (int off = 1; off < 256; off <<= 1) {
        int x = (t >= off) ? s[t - off] : 0;
        __syncthreads();
        s[t] += x;
        __syncthreads();
    }
    if (t < NBLK) boff[t] = s[t] - v;   // exclusive
}
__global__ __launch_bounds__(256) void scan3_k(const int* __restrict__ tmp, const int* __restrict__ indeg,
                                               const int* __restrict__ boff, int* __restrict__ rowptr) {
    int i = blockIdx.x * 256 + threadIdx.x;
    if (i < NN) rowptr[i] = tmp[i] - indeg[i] + boff[i >> 8];
    if (i == 0) rowptr[NN] = NE;
}
__global__ __launch_bounds__(256) void fill_k(const int* __restrict__ src, const int* __restrict__ dst,
                                              const float* __restrict__ dinv, const int* __restrict__ rowptr,
                                              int* __restrict__ cursor, int* __restrict__ ebuf,
                                              float* __restrict__ nbuf) {
    int e = blockIdx.x * 256 + threadIdx.x;
    if (e >= NE) return;
    int s = src[e], d = dst[e];
    int pos = atomicAdd(&cursor[d], 1);
    int idx = rowptr[d] + pos;
    ebuf[idx] = s;
    nbuf[idx] = dinv[s] * dinv[d];
}

// ---------------- merged weight cast+transpose (9 segments, one launch) ----------------
struct WSegs {
    const float* W[9];
    unsigned short* Wt[9];
    int K[9], N[9], Kp[9];
    int c0[10];   // cumulative 256-elem chunk offsets
};
__global__ __launch_bounds__(256) void wcast_all_k(WSegs s) {
    int blk = blockIdx.x;
    #pragma unroll
    for (int g = 0; g < 9; g++) {
        if (blk >= s.c0[g] && blk < s.c0[g + 1]) {
            int idx = (blk - s.c0[g]) * 256 + threadIdx.x;
            int Kp = s.Kp[g];
            int n = idx / Kp, k = idx % Kp;
            float v = (n < s.N[g] && k < s.K[g]) ? s.W[g][(size_t)k * s.N[g] + n] : 0.0f;
            s.Wt[g][idx] = f2b(v);   // idx always < Kp*Np (chunks exact: sizes are multiples of 256)
        }
    }
}

// ---------------- MFMA bf16 GEMM: C[M x ldc](bf16) = A @ Wt^T (+bias) ----------------
// BM=128, BK=64, 4 waves; BN in {64,128}; wave tile 64 x BN/2.
template<bool AF32, int BN>
__global__ __launch_bounds__(256) void gemm_mfma_k(
    const void* __restrict__ Araw, const unsigned short* __restrict__ Bt,
    const float* __restrict__ bias, unsigned short* __restrict__ C,
    int M, int lda, int Kp, int N, int ldc) {
    constexpr int NF = BN / 32;
    __shared__ char lds[16384 + BN * 128];
    char* AsB = lds;
    char* BsB = lds + 16384;

    int tid  = threadIdx.x;
    int lane = tid & 63;
    int wave = tid >> 6;
    int wr = wave >> 1, wc = wave & 1;
    int lr = lane & 15, lk = lane >> 4;
    int r0 = blockIdx.x * 128;
    int c0 = blockIdx.y * BN;

    f32x4 acc[4][NF];
    #pragma unroll
    for (int m = 0; m < 4; m++)
        #pragma unroll
        for (int n = 0; n < NF; n++)
            acc[m][n] = (f32x4){0.f, 0.f, 0.f, 0.f};

    for (int k0 = 0; k0 < Kp; k0 += 64) {
        // stage A tile -> bf16 LDS (128 rows x 64 k)
        #pragma unroll
        for (int c = 0; c < 4; c++) {
            int o = tid + c * 256;
            int row = o >> 3, oct = o & 7;
            int gr = r0 + row;
            short8 v = {0, 0, 0, 0, 0, 0, 0, 0};
            if (AF32) {
                if (gr < M) {
                    const float* p = (const float*)Araw + (size_t)gr * lda + k0 + oct * 8;
                    float4 f0 = *(const float4*)p;
                    float4 f1 = *(const float4*)(p + 4);
                    v[0] = (short)f2b(f0.x); v[1] = (short)f2b(f0.y);
                    v[2] = (short)f2b(f0.z); v[3] = (short)f2b(f0.w);
                    v[4] = (short)f2b(f1.x); v[5] = (short)f2b(f1.y);
                    v[6] = (short)f2b(f1.z); v[7] = (short)f2b(f1.w);
                }
            } else {
                if (gr < M)
                    v = *(const short8*)((const unsigned short*)Araw + (size_t)gr * lda + k0 + oct * 8);
            }
            *(short8*)(AsB + SWZ(row * 128 + oct * 16, row)) = v;
        }
        // stage B tile (BN rows x 64 k)
        #pragma unroll
        for (int c = 0; c < BN / 32; c++) {
            int o = tid + c * 256;
            int row = o >> 3, oct = o & 7;
            short8 v = *(const short8*)(Bt + (size_t)(c0 + row) * Kp + k0 + oct * 8);
            *(short8*)(BsB + SWZ(row * 128 + oct * 16, row)) = v;
        }
        __syncthreads();
        #pragma unroll
        for (int kk = 0; kk < 2; kk++) {
            int kb = kk * 64 + lk * 16;
            short8 a[4], b[NF];
            #pragma unroll
            for (int m = 0; m < 4; m++) {
                int row = wr * 64 + m * 16 + lr;
                a[m] = *(short8*)(AsB + SWZ(row * 128 + kb, row));
            }
            #pragma unroll
            for (int n = 0; n < NF; n++) {
                int row = wc * (BN / 2) + n * 16 + lr;
                b[n] = *(short8*)(BsB + SWZ(row * 128 + kb, row));
            }
            #pragma unroll
            for (int m = 0; m < 4; m++)
                #pragma unroll
                for (int n = 0; n < NF; n++)
                    acc[m][n] = __builtin_amdgcn_mfma_f32_16x16x32_bf16(a[m], b[n], acc[m][n], 0, 0, 0);
        }
        __syncthreads();
    }
    // epilogue: C/D layout col=lane&15, row=(lane>>4)*4+j ; write bf16
    #pragma unroll
    for (int n = 0; n < NF; n++) {
        int gc = c0 + wc * (BN / 2) + n * 16 + lr;
        float bv = (bias && gc < N) ? bias[gc] : 0.0f;
        #pragma unroll
        for (int m = 0; m < 4; m++) {
            #pragma unroll
            for (int j = 0; j < 4; j++) {
                int gr = r0 + wr * 64 + m * 16 + lk * 4 + j;
                if (gr < M) {
                    float v = (gc < N) ? acc[m][n][j] + bv : 0.0f;
                    C[(size_t)gr * ldc + gc] = f2b(v);
                }
            }
        }
    }
}

// ---------------- fused GCN aggregate + combine (CSR gather, bf16 h/base) ----------------
template<int VEC> struct BV;
template<> struct BV<1> { using T = unsigned short; };
template<> struct BV<2> { using T = u16x2; };
template<> struct BV<4> { using T = u16x4; };

// out[n] = base[n] + alpha * maybe_relu( sum_e norm_e*h[src_e] + h[n]*dinv[n]^2 + bias )
template<int VEC, bool OUTF32>
__global__ __launch_bounds__(256) void gather_k(
    const unsigned short* __restrict__ h, const unsigned short* __restrict__ base,
    const float* __restrict__ dinv, const float* __restrict__ bias,
    const int* __restrict__ ebuf, const float* __restrict__ nbuf,
    const int* __restrict__ rowptr, void* __restrict__ outraw,
    float alpha, int dorelu, int F) {
    const int ld = 64 * VEC;
    int w = (blockIdx.x * 256 + threadIdx.x) >> 6;
    int lane = threadIdx.x & 63;
    if (w >= NN) return;
    using LT = typename BV<VEC>::T;

    float acc[VEC];
    float dn = dinv[w];
    {
        LT t = *(const LT*)(h + (size_t)w * ld + lane * VEC);
        const unsigned short* tu = (const unsigned short*)&t;
        #pragma unroll
        for (int v = 0; v < VEC; v++) acc[v] = b2f(tu[v]) * dn * dn;
    }
    int e = rowptr[w], end = rowptr[w + 1];
    for (; e + 2 <= end; e += 2) {
        int s0 = ebuf[e], s1 = ebuf[e + 1];
        float n0 = nbuf[e], n1 = nbuf[e + 1];
        LT t0 = *(const LT*)(h + (size_t)s0 * ld + lane * VEC);
        LT t1 = *(const LT*)(h + (size_t)s1 * ld + lane * VEC);
        const unsigned short* u0 = (const unsigned short*)&t0;
        const unsigned short* u1 = (const unsigned short*)&t1;
        #pragma unroll
        for (int v = 0; v < VEC; v++) acc[v] += b2f(u0[v]) * n0 + b2f(u1[v]) * n1;
    }
    if (e < end) {
        int s0 = ebuf[e];
        float n0 = nbuf[e];
        LT t0 = *(const LT*)(h + (size_t)s0 * ld + lane * VEC);
        const unsigned short* u0 = (const unsigned short*)&t0;
        #pragma unroll
        for (int v = 0; v < VEC; v++) acc[v] += b2f(u0[v]) * n0;
    }
    LT bt = *(const LT*)(base + (size_t)w * ld + lane * VEC);
    const unsigned short* bu = (const unsigned short*)&bt;
    #pragma unroll
    for (int v = 0; v < VEC; v++) {
        int f = lane * VEC + v;
        float a = acc[v] + ((f < F) ? bias[f] : 0.0f);
        if (dorelu) a = fmaxf(a, 0.0f);
        float res = (f < F) ? b2f(bu[v]) + alpha * a : 0.0f;
        if (OUTF32) {
            ((float*)outraw)[(size_t)w * ld + f] = res;
        } else {
            ((unsigned short*)outraw)[(size_t)w * ld + f] = f2b(res);
        }
    }
}

extern "C" void kernel_launch(void* const* d_in, const int* in_sizes, int n_in,
                              void* d_out, int out_size, void* d_ws, size_t ws_size,
                              hipStream_t stream) {
    const float* x   = (const float*)d_in[0];
    const int*   ei  = (const int*)d_in[1];
    const float* W1  = (const float*)d_in[2];  const float* b1  = (const float*)d_in[3];
    const float* W2  = (const float*)d_in[4];  const float* b2  = (const float*)d_in[5];
    const float* W3  = (const float*)d_in[6];  const float* b3  = (const float*)d_in[7];
    const float* Wg1 = (const float*)d_in[8];  const float* bg1 = (const float*)d_in[9];
    const float* Wg2 = (const float*)d_in[10]; const float* bg2 = (const float*)d_in[11];
    const float* Wg3 = (const float*)d_in[12]; const float* bg3 = (const float*)d_in[13];
    const float* Wg4 = (const float*)d_in[14]; const float* bg4 = (const float*)d_in[15];
    const float* Wg5 = (const float*)d_in[16]; const float* bg5 = (const float*)d_in[17];
    const float* Wg6 = (const float*)d_in[18]; const float* bg6 = (const float*)d_in[19];
    const int* srcv = ei;
    const int* dstv = ei + NE;

    float* dinv = (float*)d_ws;                         // 51200 f32
    unsigned short* hA = (unsigned short*)(dinv + 51200);   // NN x 256 bf16
    unsigned short* hB = hA + (size_t)NN * 256;
    unsigned short* hC = hB + (size_t)NN * 256;
    unsigned short* W1t  = hC + (size_t)NN * 256;  // 256x512
    unsigned short* Wg1t = W1t  + 256 * 512;       // 256x256
    unsigned short* W2t  = Wg1t + 256 * 256;       // 64x256
    unsigned short* Wg2t = W2t  + 64 * 256;        // 64x64
    unsigned short* W3t  = Wg2t + 64 * 64;         // 128x64
    unsigned short* Wg3t = W3t  + 128 * 64;        // 128x128
    unsigned short* Wg4t = Wg3t + 128 * 128;
    unsigned short* Wg5t = Wg4t + 128 * 128;
    unsigned short* Wg6t = Wg5t + 128 * 128;
    int* indeg  = (int*)(Wg6t + 128 * 128);
    int* cursor = indeg + 51200;
    int* tmp    = cursor + 51200;
    int* rowptr = tmp + 51200;                     // 51264
    int* bsum   = rowptr + 51264;
    int* boff   = bsum + 256;
    int* ebuf   = boff + 256;                      // 400000
    float* nbuf = (float*)(ebuf + 400000);         // 400000

    // CSR + dinv
    zero2_k<<<NBLK, 256, 0, stream>>>(indeg, cursor);
    count_k<<<(NE + 255) / 256, 256, 0, stream>>>(dstv, indeg);
    dinv_k<<<NBLK, 256, 0, stream>>>(indeg, dinv);
    scan1_k<<<NBLK, 256, 0, stream>>>(indeg, tmp, bsum);
    scan2_k<<<1, 256, 0, stream>>>(bsum, boff);
    scan3_k<<<NBLK, 256, 0, stream>>>(tmp, indeg, boff, rowptr);
    fill_k<<<(NE + 255) / 256, 256, 0, stream>>>(srcv, dstv, dinv, rowptr, cursor, ebuf, nbuf);

    // weights: one merged cast+transpose launch
    {
        WSegs s;
        const float* Ws[9] = {W1, Wg1, W2, Wg2, W3, Wg3, Wg4, Wg5, Wg6};
        unsigned short* Wts[9] = {W1t, Wg1t, W2t, Wg2t, W3t, Wg3t, Wg4t, Wg5t, Wg6t};
        int Ks[9]  = {512, 256, 256, 62, 62, 128, 128, 128, 128};
        int Ns[9]  = {256, 256, 62, 62, 128, 128, 128, 128, 128};
        int Kps[9] = {512, 256, 256, 64, 64, 128, 128, 128, 128};
        int Nps[9] = {256, 256, 64, 64, 128, 128, 128, 128, 128};
        int c = 0;
        for (int g = 0; g < 9; g++) {
            s.W[g] = Ws[g]; s.Wt[g] = Wts[g];
            s.K[g] = Ks[g]; s.N[g] = Ns[g]; s.Kp[g] = Kps[g];
            s.c0[g] = c;
            c += (Kps[g] * Nps[g]) / 256;
        }
        s.c0[9] = c;
        wcast_all_k<<<c, 256, 0, stream>>>(s);
    }

    auto gemm = [&](const void* Ain, int lda, int Kp, const unsigned short* Bt,
                    const float* bias, unsigned short* Cout, int N, int ldc, bool af32) {
        if (ldc >= 128) {
            dim3 grid((NN + 127) / 128, ldc / 128);
            if (af32) gemm_mfma_k<true, 128><<<grid, 256, 0, stream>>>(Ain, Bt, bias, Cout, NN, lda, Kp, N, ldc);
            else      gemm_mfma_k<false, 128><<<grid, 256, 0, stream>>>(Ain, Bt, bias, Cout, NN, lda, Kp, N, ldc);
        } else {
            dim3 grid((NN + 127) / 128, ldc / 64);
            if (af32) gemm_mfma_k<true, 64><<<grid, 256, 0, stream>>>(Ain, Bt, bias, Cout, NN, lda, Kp, N, ldc);
            else      gemm_mfma_k<false, 64><<<grid, 256, 0, stream>>>(Ain, Bt, bias, Cout, NN, lda, Kp, N, ldc);
        }
    };
    const int GG = (NN * 64 + 255) / 256;   // one wave per node

    // L1: x1l -> hA ; h -> hB ; x1 -> hC    (ld 256)
    gemm(x, 512, 512, W1t, b1, hA, 256, 256, true);
    gemm(hA, 256, 256, Wg1t, nullptr, hB, 256, 256, false);
    gather_k<4, false><<<GG, 256, 0, stream>>>(hB, hA, dinv, bg1, ebuf, nbuf, rowptr, hC, 1.0f, 1, 256);
    // L2: x2l -> hA ; h -> hB ; x2 -> hC    (ld 64)
    gemm(hC, 256, 256, W2t, b2, hA, 62, 64, false);
    gemm(hA, 64, 64, Wg2t, nullptr, hB, 62, 64, false);
    gather_k<1, false><<<GG, 256, 0, stream>>>(hB, hA, dinv, bg2, ebuf, nbuf, rowptr, hC, 1.0f, 1, 62);
    // L3: x3l -> hA ; h -> hB ; x3 -> hC    (ld 128)
    gemm(hC, 64, 64, W3t, b3, hA, 128, 128, false);
    gemm(hA, 128, 128, Wg3t, nullptr, hB, 128, 128, false);
    gather_k<2, false><<<GG, 256, 0, stream>>>(hB, hA, dinv, bg3, ebuf, nbuf, rowptr, hC, 0.5f, 1, 128);
    // L4: h -> hA ; x4 -> hB
    gemm(hC, 128, 128, Wg4t, nullptr, hA, 128, 128, false);
    gather_k<2, false><<<GG, 256, 0, stream>>>(hA, hC, dinv, bg4, ebuf, nbuf, rowptr, hB, 0.5f, 1, 128);
    // L5: h -> hA ; x5 -> hC
    gemm(hB, 128, 128, Wg5t, nullptr, hA, 128, 128, false);
    gather_k<2, false><<<GG, 256, 0, stream>>>(hA, hB, dinv, bg5, ebuf, nbuf, rowptr, hC, 0.25f, 1, 128);
    // L6: h -> hA ; x6 -> d_out (fp32)
    gemm(hC, 128, 128, Wg6t, nullptr, hA, 128, 128, false);
    gather_k<2, true><<<GG, 256, 0, stream>>>(hA, hC, dinv, bg6, ebuf, nbuf, rowptr, d_out, 0.25f, 0, 128);
}

// Round 5
// 383.550 us; speedup vs baseline: 5.5647x; 1.3081x over previous
//
#include <hip/hip_runtime.h>

#define NN 50000
#define NE 400000
#define NBLK 196   // ceil(NN/256)

using short8 = __attribute__((ext_vector_type(8))) short;
using f32x4  = __attribute__((ext_vector_type(4))) float;
using u16x2  = __attribute__((ext_vector_type(2))) unsigned short;
using u16x4  = __attribute__((ext_vector_type(4))) unsigned short;

__device__ __forceinline__ unsigned short f2b(float f) {
    union { float f; unsigned int u; } x; x.f = f;
    unsigned int u = x.u;
    u += 0x7fffu + ((u >> 16) & 1u);   // RNE
    return (unsigned short)(u >> 16);
}
__device__ __forceinline__ float b2f(unsigned short u) {
    union { unsigned int u; float f; } x; x.u = ((unsigned int)u) << 16;
    return x.f;
}

#define SWZ(b, row) ((b) ^ (((row) & 7) << 4))

// ---------------- CSR build ----------------
__global__ __launch_bounds__(256) void zero2_k(int* a, int* b) {
    int i = blockIdx.x * 256 + threadIdx.x;
    if (i < NN) { a[i] = 0; b[i] = 0; }
}
__global__ __launch_bounds__(256) void count_k(const int* __restrict__ dst, int* __restrict__ indeg) {
    int e = blockIdx.x * 256 + threadIdx.x;
    if (e < NE) atomicAdd(&indeg[dst[e]], 1);
}
__global__ __launch_bounds__(256) void dinv_k(const int* __restrict__ indeg, float* __restrict__ dinv) {
    int i = blockIdx.x * 256 + threadIdx.x;
    if (i < NN) dinv[i] = rsqrtf((float)(1 + indeg[i]));
}
__global__ __launch_bounds__(256) void scan1_k(const int* __restrict__ indeg, int* __restrict__ tmp,
                                               int* __restrict__ bsum) {
    __shared__ int s[256];
    int t = threadIdx.x, i = blockIdx.x * 256 + t;
    int v = (i < NN) ? indeg[i] : 0;
    s[t] = v; __syncthreads();
    for (int off = 1; off < 256; off <<= 1) {
        int x = (t >= off) ? s[t - off] : 0;
        __syncthreads();
        s[t] += x;
        __syncthreads();
    }
    if (i < NN) tmp[i] = s[t];
    if (t == 255) bsum[blockIdx.x] = s[255];
}
__global__ __launch_bounds__(256) void scan2_k(const int* __restrict__ bsum, int* __restrict__ boff) {
    __shared__ int s[256];
    int t = threadIdx.x;
    int v = (t < NBLK) ? bsum[t] : 0;
    s[t] = v; __syncthreads();
    for (int off = 1; off < 256; off <<= 1) {
        int x = (t >= off) ? s[t - off] : 0;
        __syncthreads();
        s[t] += x;
        __syncthreads();
    }
    if (t < NBLK) boff[t] = s[t] - v;   // exclusive
}
__global__ __launch_bounds__(256) void scan3_k(const int* __restrict__ tmp, const int* __restrict__ indeg,
                                               const int* __restrict__ boff, int* __restrict__ rowptr) {
    int i = blockIdx.x * 256 + threadIdx.x;
    if (i < NN) rowptr[i] = tmp[i] - indeg[i] + boff[i >> 8];
    if (i == 0) rowptr[NN] = NE;
}
__global__ __launch_bounds__(256) void fill_k(const int* __restrict__ src, const int* __restrict__ dst,
                                              const float* __restrict__ dinv, const int* __restrict__ rowptr,
                                              int* __restrict__ cursor, int2* __restrict__ ebn) {
    int e = blockIdx.x * 256 + threadIdx.x;
    if (e >= NE) return;
    int s = src[e], d = dst[e];
    int pos = atomicAdd(&cursor[d], 1);
    ebn[rowptr[d] + pos] = make_int2(s, __float_as_int(dinv[s] * dinv[d]));
}

// ---------------- merged weight cast+transpose (9 segments, one launch) ----------------
struct WSegs {
    const float* W[9];
    unsigned short* Wt[9];
    int K[9], N[9], Kp[9];
    int c0[10];
};
__global__ __launch_bounds__(256) void wcast_all_k(WSegs s) {
    int blk = blockIdx.x;
    #pragma unroll
    for (int g = 0; g < 9; g++) {
        if (blk >= s.c0[g] && blk < s.c0[g + 1]) {
            int idx = (blk - s.c0[g]) * 256 + threadIdx.x;
            int Kp = s.Kp[g];
            int n = idx / Kp, k = idx % Kp;
            float v = (n < s.N[g] && k < s.K[g]) ? s.W[g][(size_t)k * s.N[g] + n] : 0.0f;
            s.Wt[g][idx] = f2b(v);
        }
    }
}

// ---------------- MFMA bf16 GEMM with reg-staged prefetch + LDS-exchange epilogue ------
// C[M x ldc](bf16) = A[M x lda] @ Wt[ldc x Kp]^T (+bias). BM=64, BK=64, 4 waves (2x2).
template<bool AF32, int BM, int BN>
__global__ __launch_bounds__(256) void gemm_mfma_k(
    const void* __restrict__ Araw, const unsigned short* __restrict__ Bt,
    const float* __restrict__ bias, unsigned short* __restrict__ C,
    int M, int lda, int Kp, int N, int ldc) {
    constexpr int MR = BM / 32;      // a-frags per wave
    constexpr int NF = BN / 32;      // b-frags per wave
    constexpr int nA = BM / 32;      // A 16B-chunks per thread
    constexpr int nB = BN / 32;
    __shared__ __align__(16) char lds[BM * 128 + BN * 128];
    char* AsB = lds;
    char* BsB = lds + BM * 128;

    int tid = threadIdx.x;
    int lane = tid & 63, wave = tid >> 6;
    int wr = wave >> 1, wc = wave & 1;
    int lr = lane & 15, lk = lane >> 4;
    int r0 = blockIdx.x * BM, c0 = blockIdx.y * BN;

    f32x4 acc[MR][NF];
    #pragma unroll
    for (int m = 0; m < MR; m++)
        #pragma unroll
        for (int n = 0; n < NF; n++)
            acc[m][n] = (f32x4){0.f, 0.f, 0.f, 0.f};

    float4 fa0[nA], fa1[nA];
    short8 ra[nA], rb[nB];

    auto LOAD = [&](int k0) {
        #pragma unroll
        for (int c = 0; c < nA; c++) {
            int o = tid + c * 256, row = o >> 3, oct = o & 7;
            int gr = r0 + row;
            if constexpr (AF32) {
                if (gr < M) {
                    const float* p = (const float*)Araw + (size_t)gr * lda + k0 + oct * 8;
                    fa0[c] = *(const float4*)p;
                    fa1[c] = *(const float4*)(p + 4);
                } else {
                    fa0[c] = make_float4(0, 0, 0, 0);
                    fa1[c] = make_float4(0, 0, 0, 0);
                }
            } else {
                short8 z = {0, 0, 0, 0, 0, 0, 0, 0};
                ra[c] = (gr < M)
                    ? *(const short8*)((const unsigned short*)Araw + (size_t)gr * lda + k0 + oct * 8)
                    : z;
            }
        }
        #pragma unroll
        for (int c = 0; c < nB; c++) {
            int o = tid + c * 256, row = o >> 3, oct = o & 7;
            rb[c] = *(const short8*)(Bt + (size_t)(c0 + row) * Kp + k0 + oct * 8);
        }
    };
    auto STORE = [&]() {
        #pragma unroll
        for (int c = 0; c < nA; c++) {
            int o = tid + c * 256, row = o >> 3, oct = o & 7;
            short8 v;
            if constexpr (AF32) {
                v[0] = (short)f2b(fa0[c].x); v[1] = (short)f2b(fa0[c].y);
                v[2] = (short)f2b(fa0[c].z); v[3] = (short)f2b(fa0[c].w);
                v[4] = (short)f2b(fa1[c].x); v[5] = (short)f2b(fa1[c].y);
                v[6] = (short)f2b(fa1[c].z); v[7] = (short)f2b(fa1[c].w);
            } else {
                v = ra[c];
            }
            *(short8*)(AsB + SWZ(row * 128 + oct * 16, row)) = v;
        }
        #pragma unroll
        for (int c = 0; c < nB; c++) {
            int o = tid + c * 256, row = o >> 3, oct = o & 7;
            *(short8*)(BsB + SWZ(row * 128 + oct * 16, row)) = rb[c];
        }
    };

    int nt = Kp >> 6;
    LOAD(0);
    STORE();
    __syncthreads();
    for (int t = 0; t < nt; t++) {
        if (t + 1 < nt) LOAD((t + 1) << 6);   // prefetch: in flight during MFMA below
        #pragma unroll
        for (int kk = 0; kk < 2; kk++) {
            int kb = kk * 64 + lk * 16;
            short8 a[MR], b[NF];
            #pragma unroll
            for (int m = 0; m < MR; m++) {
                int row = wr * (BM / 2) + m * 16 + lr;
                a[m] = *(short8*)(AsB + SWZ(row * 128 + kb, row));
            }
            #pragma unroll
            for (int n = 0; n < NF; n++) {
                int row = wc * (BN / 2) + n * 16 + lr;
                b[n] = *(short8*)(BsB + SWZ(row * 128 + kb, row));
            }
            #pragma unroll
            for (int m = 0; m < MR; m++)
                #pragma unroll
                for (int n = 0; n < NF; n++)
                    acc[m][n] = __builtin_amdgcn_mfma_f32_16x16x32_bf16(a[m], b[n], acc[m][n], 0, 0, 0);
        }
        __syncthreads();
        if (t + 1 < nt) { STORE(); __syncthreads(); }
    }

    // epilogue: C-tile -> LDS (bf16) -> coalesced short8 global writes
    unsigned short* ldsC = (unsigned short*)lds;
    #pragma unroll
    for (int n = 0; n < NF; n++) {
        int cc = wc * (BN / 2) + n * 16 + lr;
        int gc = c0 + cc;
        float bv = (bias != nullptr && gc < N) ? bias[gc] : 0.0f;
        bool ok = gc < N;
        #pragma unroll
        for (int m = 0; m < MR; m++)
            #pragma unroll
            for (int j = 0; j < 4; j++) {
                int row = wr * (BM / 2) + m * 16 + lk * 4 + j;
                float v = ok ? acc[m][n][j] + bv : 0.0f;
                ldsC[row * BN + cc] = f2b(v);
            }
    }
    __syncthreads();
    constexpr int CH = (BM * BN) / 2048;
    #pragma unroll
    for (int c = 0; c < CH; c++) {
        int o = tid + c * 256;
        int row = o / (BN / 8), col = (o % (BN / 8)) * 8;
        int gr = r0 + row;
        if (gr < M)
            *(short8*)(C + (size_t)gr * ldc + c0 + col) = *(short8*)(ldsC + row * BN + col);
    }
}

// ---------------- fused GCN aggregate + combine (CSR gather, bf16) ----------------
template<int VEC> struct BV;
template<> struct BV<1> { using T = unsigned short; };
template<> struct BV<2> { using T = u16x2; };
template<> struct BV<4> { using T = u16x4; };

template<int VEC, bool OUTF32>
__global__ __launch_bounds__(256) void gather_k(
    const unsigned short* __restrict__ h, const unsigned short* __restrict__ base,
    const float* __restrict__ dinv, const float* __restrict__ bias,
    const int2* __restrict__ ebn, const int* __restrict__ rowptr,
    void* __restrict__ outraw, float alpha, int dorelu, int F) {
    const int ld = 64 * VEC;
    int w = (blockIdx.x * 256 + threadIdx.x) >> 6;
    int lane = threadIdx.x & 63;
    if (w >= NN) return;
    using LT = typename BV<VEC>::T;

    float acc[VEC];
    float dn = dinv[w];
    {
        LT t = *(const LT*)(h + (size_t)w * ld + lane * VEC);
        const unsigned short* tu = (const unsigned short*)&t;
        #pragma unroll
        for (int v = 0; v < VEC; v++) acc[v] = b2f(tu[v]) * dn * dn;
    }
    int e = rowptr[w], end = rowptr[w + 1];
    for (; e + 4 <= end; e += 4) {
        int2 q0 = ebn[e], q1 = ebn[e + 1], q2 = ebn[e + 2], q3 = ebn[e + 3];
        LT t0 = *(const LT*)(h + (size_t)q0.x * ld + lane * VEC);
        LT t1 = *(const LT*)(h + (size_t)q1.x * ld + lane * VEC);
        LT t2 = *(const LT*)(h + (size_t)q2.x * ld + lane * VEC);
        LT t3 = *(const LT*)(h + (size_t)q3.x * ld + lane * VEC);
        float n0 = __int_as_float(q0.y), n1 = __int_as_float(q1.y);
        float n2 = __int_as_float(q2.y), n3 = __int_as_float(q3.y);
        const unsigned short* u0 = (const unsigned short*)&t0;
        const unsigned short* u1 = (const unsigned short*)&t1;
        const unsigned short* u2 = (const unsigned short*)&t2;
        const unsigned short* u3 = (const unsigned short*)&t3;
        #pragma unroll
        for (int v = 0; v < VEC; v++)
            acc[v] += b2f(u0[v]) * n0 + b2f(u1[v]) * n1 + b2f(u2[v]) * n2 + b2f(u3[v]) * n3;
    }
    for (; e < end; e++) {
        int2 q0 = ebn[e];
        LT t0 = *(const LT*)(h + (size_t)q0.x * ld + lane * VEC);
        float n0 = __int_as_float(q0.y);
        const unsigned short* u0 = (const unsigned short*)&t0;
        #pragma unroll
        for (int v = 0; v < VEC; v++) acc[v] += b2f(u0[v]) * n0;
    }
    LT bt = *(const LT*)(base + (size_t)w * ld + lane * VEC);
    const unsigned short* bu = (const unsigned short*)&bt;
    #pragma unroll
    for (int v = 0; v < VEC; v++) {
        int f = lane * VEC + v;
        float a = acc[v] + ((f < F) ? bias[f] : 0.0f);
        if (dorelu) a = fmaxf(a, 0.0f);
        float res = (f < F) ? b2f(bu[v]) + alpha * a : 0.0f;
        if (OUTF32) ((float*)outraw)[(size_t)w * ld + f] = res;
        else        ((unsigned short*)outraw)[(size_t)w * ld + f] = f2b(res);
    }
}

extern "C" void kernel_launch(void* const* d_in, const int* in_sizes, int n_in,
                              void* d_out, int out_size, void* d_ws, size_t ws_size,
                              hipStream_t stream) {
    const float* x   = (const float*)d_in[0];
    const int*   ei  = (const int*)d_in[1];
    const float* W1  = (const float*)d_in[2];  const float* b1  = (const float*)d_in[3];
    const float* W2  = (const float*)d_in[4];  const float* b2  = (const float*)d_in[5];
    const float* W3  = (const float*)d_in[6];  const float* b3  = (const float*)d_in[7];
    const float* Wg1 = (const float*)d_in[8];  const float* bg1 = (const float*)d_in[9];
    const float* Wg2 = (const float*)d_in[10]; const float* bg2 = (const float*)d_in[11];
    const float* Wg3 = (const float*)d_in[12]; const float* bg3 = (const float*)d_in[13];
    const float* Wg4 = (const float*)d_in[14]; const float* bg4 = (const float*)d_in[15];
    const float* Wg5 = (const float*)d_in[16]; const float* bg5 = (const float*)d_in[17];
    const float* Wg6 = (const float*)d_in[18]; const float* bg6 = (const float*)d_in[19];
    const int* srcv = ei;
    const int* dstv = ei + NE;

    float* dinv = (float*)d_ws;                         // 51200 f32
    unsigned short* hA = (unsigned short*)(dinv + 51200);   // NN x 256 bf16
    unsigned short* hB = hA + (size_t)NN * 256;
    unsigned short* hC = hB + (size_t)NN * 256;
    unsigned short* W1t  = hC + (size_t)NN * 256;  // 256x512
    unsigned short* Wg1t = W1t  + 256 * 512;       // 256x256
    unsigned short* W2t  = Wg1t + 256 * 256;       // 64x256
    unsigned short* Wg2t = W2t  + 64 * 256;        // 64x64
    unsigned short* W3t  = Wg2t + 64 * 64;         // 128x64
    unsigned short* Wg3t = W3t  + 128 * 64;        // 128x128
    unsigned short* Wg4t = Wg3t + 128 * 128;
    unsigned short* Wg5t = Wg4t + 128 * 128;
    unsigned short* Wg6t = Wg5t + 128 * 128;
    int* indeg  = (int*)(Wg6t + 128 * 128);
    int* cursor = indeg + 51200;
    int* tmp    = cursor + 51200;
    int* rowptr = tmp + 51200;                     // 51264
    int* bsum   = rowptr + 51264;
    int* boff   = bsum + 256;
    int2* ebn   = (int2*)(boff + 256);             // 400000 x 8B

    // CSR + dinv
    zero2_k<<<NBLK, 256, 0, stream>>>(indeg, cursor);
    count_k<<<(NE + 255) / 256, 256, 0, stream>>>(dstv, indeg);
    dinv_k<<<NBLK, 256, 0, stream>>>(indeg, dinv);
    scan1_k<<<NBLK, 256, 0, stream>>>(indeg, tmp, bsum);
    scan2_k<<<1, 256, 0, stream>>>(bsum, boff);
    scan3_k<<<NBLK, 256, 0, stream>>>(tmp, indeg, boff, rowptr);
    fill_k<<<(NE + 255) / 256, 256, 0, stream>>>(srcv, dstv, dinv, rowptr, cursor, ebn);

    // weights: one merged cast+transpose launch
    {
        WSegs s;
        const float* Ws[9] = {W1, Wg1, W2, Wg2, W3, Wg3, Wg4, Wg5, Wg6};
        unsigned short* Wts[9] = {W1t, Wg1t, W2t, Wg2t, W3t, Wg3t, Wg4t, Wg5t, Wg6t};
        int Ks[9]  = {512, 256, 256, 62, 62, 128, 128, 128, 128};
        int Ns[9]  = {256, 256, 62, 62, 128, 128, 128, 128, 128};
        int Kps[9] = {512, 256, 256, 64, 64, 128, 128, 128, 128};
        int Nps[9] = {256, 256, 64, 64, 128, 128, 128, 128, 128};
        int c = 0;
        for (int g = 0; g < 9; g++) {
            s.W[g] = Ws[g]; s.Wt[g] = Wts[g];
            s.K[g] = Ks[g]; s.N[g] = Ns[g]; s.Kp[g] = Kps[g];
            s.c0[g] = c;
            c += (Kps[g] * Nps[g]) / 256;
        }
        s.c0[9] = c;
        wcast_all_k<<<c, 256, 0, stream>>>(s);
    }

    const int GX = (NN + 63) / 64;          // 782
    const int GG = (NN * 64 + 255) / 256;   // one wave per node

    // L1: x1l -> hA ; h -> hB ; x1 -> hC   (ld 256)
    gemm_mfma_k<true, 64, 128><<<dim3(GX, 2), 256, 0, stream>>>(x, W1t, b1, hA, NN, 512, 512, 256, 256);
    gemm_mfma_k<false, 64, 128><<<dim3(GX, 2), 256, 0, stream>>>(hA, Wg1t, nullptr, hB, NN, 256, 256, 256, 256);
    gather_k<4, false><<<GG, 256, 0, stream>>>(hB, hA, dinv, bg1, ebn, rowptr, hC, 1.0f, 1, 256);
    // L2: x2l -> hA ; h -> hB ; x2 -> hC   (ld 64)
    gemm_mfma_k<false, 64, 64><<<dim3(GX, 1), 256, 0, stream>>>(hC, W2t, b2, hA, NN, 256, 256, 62, 64);
    gemm_mfma_k<false, 64, 64><<<dim3(GX, 1), 256, 0, stream>>>(hA, Wg2t, nullptr, hB, NN, 64, 64, 62, 64);
    gather_k<1, false><<<GG, 256, 0, stream>>>(hB, hA, dinv, bg2, ebn, rowptr, hC, 1.0f, 1, 62);
    // L3: x3l -> hA ; h -> hB ; x3 -> hC   (ld 128)
    gemm_mfma_k<false, 64, 128><<<dim3(GX, 1), 256, 0, stream>>>(hC, W3t, b3, hA, NN, 64, 64, 128, 128);
    gemm_mfma_k<false, 64, 128><<<dim3(GX, 1), 256, 0, stream>>>(hA, Wg3t, nullptr, hB, NN, 128, 128, 128, 128);
    gather_k<2, false><<<GG, 256, 0, stream>>>(hB, hA, dinv, bg3, ebn, rowptr, hC, 0.5f, 1, 128);
    // L4: h -> hA ; x4 -> hB
    gemm_mfma_k<false, 64, 128><<<dim3(GX, 1), 256, 0, stream>>>(hC, Wg4t, nullptr, hA, NN, 128, 128, 128, 128);
    gather_k<2, false><<<GG, 256, 0, stream>>>(hA, hC, dinv, bg4, ebn, rowptr, hB, 0.5f, 1, 128);
    // L5: h -> hA ; x5 -> hC
    gemm_mfma_k<false, 64, 128><<<dim3(GX, 1), 256, 0, stream>>>(hB, Wg5t, nullptr, hA, NN, 128, 128, 128, 128);
    gather_k<2, false><<<GG, 256, 0, stream>>>(hA, hB, dinv, bg5, ebn, rowptr, hC, 0.25f, 1, 128);
    // L6: h -> hA ; x6 -> d_out (fp32)
    gemm_mfma_k<false, 64, 128><<<dim3(GX, 1), 256, 0, stream>>>(hC, Wg6t, nullptr, hA, NN, 128, 128, 128, 128);
    gather_k<2, true><<<GG, 256, 0, stream>>>(hA, hC, dinv, bg6, ebn, rowptr, d_out, 0.25f, 0, 128);
}

// Round 6
// 383.127 us; speedup vs baseline: 5.5708x; 1.0011x over previous
//
#include <hip/hip_runtime.h>

#define NN 50000
#define NE 400000
#define NBLK 196   // ceil(NN/256)

using short8 = __attribute__((ext_vector_type(8))) short;
using f32x4  = __attribute__((ext_vector_type(4))) float;
using u16x2  = __attribute__((ext_vector_type(2))) unsigned short;
using u16x4  = __attribute__((ext_vector_type(4))) unsigned short;

__device__ __forceinline__ unsigned short f2b(float f) {
    union { float f; unsigned int u; } x; x.f = f;
    unsigned int u = x.u;
    u += 0x7fffu + ((u >> 16) & 1u);   // RNE
    return (unsigned short)(u >> 16);
}
__device__ __forceinline__ float b2f(unsigned short u) {
    union { unsigned int u; float f; } x; x.u = ((unsigned int)u) << 16;
    return x.f;
}

#define SWZ(b, row) ((b) ^ (((row) & 7) << 4))

// ---------------- CSR build ----------------
__global__ __launch_bounds__(256) void zero2_k(int* a, int* b) {
    int i = blockIdx.x * 256 + threadIdx.x;
    if (i < NN) { a[i] = 0; b[i] = 0; }
}
__global__ __launch_bounds__(256) void count_k(const int* __restrict__ dst, int* __restrict__ indeg) {
    int e = blockIdx.x * 256 + threadIdx.x;
    if (e < NE) atomicAdd(&indeg[dst[e]], 1);
}
__global__ __launch_bounds__(256) void scan1_k(const int* __restrict__ indeg, int* __restrict__ tmp,
                                               int* __restrict__ bsum) {
    __shared__ int s[256];
    int t = threadIdx.x, i = blockIdx.x * 256 + t;
    int v = (i < NN) ? indeg[i] : 0;
    s[t] = v; __syncthreads();
    for (int off = 1; off < 256; off <<= 1) {
        int x = (t >= off) ? s[t - off] : 0;
        __syncthreads();
        s[t] += x;
        __syncthreads();
    }
    if (i < NN) tmp[i] = s[t];
    if (t == 255) bsum[blockIdx.x] = s[255];
}
__global__ __launch_bounds__(256) void scan2_k(const int* __restrict__ bsum, int* __restrict__ boff) {
    __shared__ int s[256];
    int t = threadIdx.x;
    int v = (t < NBLK) ? bsum[t] : 0;
    s[t] = v; __syncthreads();
    for (int off = 1; off < 256; off <<= 1) {
        int x = (t >= off) ? s[t - off] : 0;
        __syncthreads();
        s[t] += x;
        __syncthreads();
    }
    if (t < NBLK) boff[t] = s[t] - v;   // exclusive
}
// rowptr + dinv in one pass
__global__ __launch_bounds__(256) void scan3_k(const int* __restrict__ tmp, const int* __restrict__ indeg,
                                               const int* __restrict__ boff, int* __restrict__ rowptr,
                                               float* __restrict__ dinv) {
    int i = blockIdx.x * 256 + threadIdx.x;
    if (i < NN) {
        rowptr[i] = tmp[i] - indeg[i] + boff[i >> 8];
        dinv[i] = rsqrtf((float)(1 + indeg[i]));
    }
    if (i == 0) rowptr[NN] = NE;
}
__global__ __launch_bounds__(256) void fill_k(const int* __restrict__ src, const int* __restrict__ dst,
                                              const float* __restrict__ dinv, const int* __restrict__ rowptr,
                                              int* __restrict__ cursor, int2* __restrict__ ebn) {
    int e = blockIdx.x * 256 + threadIdx.x;
    if (e >= NE) return;
    int s = src[e], d = dst[e];
    int pos = atomicAdd(&cursor[d], 1);
    ebn[rowptr[d] + pos] = make_int2(s, __float_as_int(dinv[s] * dinv[d]));
}

// ---------------- merged weight cast+transpose (9 segments, one launch) ----------------
struct WSegs {
    const float* W[9];
    unsigned short* Wt[9];
    int K[9], N[9], Kp[9];
    int c0[10];
};
__global__ __launch_bounds__(256) void wcast_all_k(WSegs s) {
    int blk = blockIdx.x;
    #pragma unroll
    for (int g = 0; g < 9; g++) {
        if (blk >= s.c0[g] && blk < s.c0[g + 1]) {
            int idx = (blk - s.c0[g]) * 256 + threadIdx.x;
            int Kp = s.Kp[g];
            int n = idx / Kp, k = idx % Kp;
            float v = (n < s.N[g] && k < s.K[g]) ? s.W[g][(size_t)k * s.N[g] + n] : 0.0f;
            s.Wt[g][idx] = f2b(v);
        }
    }
}

// ---------------- MFMA bf16 GEMM: double-buffered LDS, reg prefetch, 1 barrier/K-step --
// C[M x ldc](bf16) = A[M x lda] @ Wt[ldc x Kp]^T (+bias). 4 waves (2x2).
template<bool AF32, int BM, int BN>
__global__ __launch_bounds__(256) void gemm_mfma_k(
    const void* __restrict__ Araw, const unsigned short* __restrict__ Bt,
    const float* __restrict__ bias, unsigned short* __restrict__ C,
    int M, int lda, int Kp, int N, int ldc) {
    constexpr int MR = BM / 32;
    constexpr int NF = BN / 32;
    constexpr int nA = BM / 32;
    constexpr int nB = BN / 32;
    constexpr int BUFB = (BM + BN) * 128;     // bytes per LDS buffer
    __shared__ __align__(16) char lds[2 * BUFB];

    int tid = threadIdx.x;
    int lane = tid & 63, wave = tid >> 6;
    int wr = wave >> 1, wc = wave & 1;
    int lr = lane & 15, lk = lane >> 4;
    int r0 = blockIdx.x * BM, c0 = blockIdx.y * BN;

    f32x4 acc[MR][NF];
    #pragma unroll
    for (int m = 0; m < MR; m++)
        #pragma unroll
        for (int n = 0; n < NF; n++)
            acc[m][n] = (f32x4){0.f, 0.f, 0.f, 0.f};

    float4 fa0[nA], fa1[nA];
    short8 ra[nA], rb[nB];

    auto LOAD = [&](int k0) {
        #pragma unroll
        for (int c = 0; c < nA; c++) {
            int o = tid + c * 256, row = o >> 3, oct = o & 7;
            int gr = r0 + row;
            if constexpr (AF32) {
                if (gr < M) {
                    const float* p = (const float*)Araw + (size_t)gr * lda + k0 + oct * 8;
                    fa0[c] = *(const float4*)p;
                    fa1[c] = *(const float4*)(p + 4);
                } else {
                    fa0[c] = make_float4(0, 0, 0, 0);
                    fa1[c] = make_float4(0, 0, 0, 0);
                }
            } else {
                short8 z = {0, 0, 0, 0, 0, 0, 0, 0};
                ra[c] = (gr < M)
                    ? *(const short8*)((const unsigned short*)Araw + (size_t)gr * lda + k0 + oct * 8)
                    : z;
            }
        }
        #pragma unroll
        for (int c = 0; c < nB; c++) {
            int o = tid + c * 256, row = o >> 3, oct = o & 7;
            rb[c] = *(const short8*)(Bt + (size_t)(c0 + row) * Kp + k0 + oct * 8);
        }
    };
    auto STORE = [&](char* AsB, char* BsB) {
        #pragma unroll
        for (int c = 0; c < nA; c++) {
            int o = tid + c * 256, row = o >> 3, oct = o & 7;
            short8 v;
            if constexpr (AF32) {
                v[0] = (short)f2b(fa0[c].x); v[1] = (short)f2b(fa0[c].y);
                v[2] = (short)f2b(fa0[c].z); v[3] = (short)f2b(fa0[c].w);
                v[4] = (short)f2b(fa1[c].x); v[5] = (short)f2b(fa1[c].y);
                v[6] = (short)f2b(fa1[c].z); v[7] = (short)f2b(fa1[c].w);
            } else {
                v = ra[c];
            }
            *(short8*)(AsB + SWZ(row * 128 + oct * 16, row)) = v;
        }
        #pragma unroll
        for (int c = 0; c < nB; c++) {
            int o = tid + c * 256, row = o >> 3, oct = o & 7;
            *(short8*)(BsB + SWZ(row * 128 + oct * 16, row)) = rb[c];
        }
    };

    int nt = Kp >> 6;
    LOAD(0);
    STORE(lds, lds + BM * 128);
    __syncthreads();
    for (int t = 0; t < nt; t++) {
        char* cur = lds + (t & 1) * BUFB;
        char* alt = lds + ((t + 1) & 1) * BUFB;
        if (t + 1 < nt) LOAD((t + 1) << 6);     // global loads in flight during MFMA
        char* AsB = cur;
        char* BsB = cur + BM * 128;
        #pragma unroll
        for (int kk = 0; kk < 2; kk++) {
            int kb = kk * 64 + lk * 16;
            short8 a[MR], b[NF];
            #pragma unroll
            for (int m = 0; m < MR; m++) {
                int row = wr * (BM / 2) + m * 16 + lr;
                a[m] = *(short8*)(AsB + SWZ(row * 128 + kb, row));
            }
            #pragma unroll
            for (int n = 0; n < NF; n++) {
                int row = wc * (BN / 2) + n * 16 + lr;
                b[n] = *(short8*)(BsB + SWZ(row * 128 + kb, row));
            }
            #pragma unroll
            for (int m = 0; m < MR; m++)
                #pragma unroll
                for (int n = 0; n < NF; n++)
                    acc[m][n] = __builtin_amdgcn_mfma_f32_16x16x32_bf16(a[m], b[n], acc[m][n], 0, 0, 0);
        }
        if (t + 1 < nt) STORE(alt, alt + BM * 128);   // vmcnt wait lands here, after MFMA
        __syncthreads();
    }

    // epilogue: acc -> LDS (padded) -> coalesced short8 global writes
    constexpr int LDC = BN + 8;   // +16B pad: keeps short8 alignment, breaks bank aliasing
    unsigned short* ldsC = (unsigned short*)lds;
    #pragma unroll
    for (int n = 0; n < NF; n++) {
        int cc = wc * (BN / 2) + n * 16 + lr;
        int gc = c0 + cc;
        float bv = (bias != nullptr && gc < N) ? bias[gc] : 0.0f;
        bool ok = gc < N;
        #pragma unroll
        for (int m = 0; m < MR; m++)
            #pragma unroll
            for (int j = 0; j < 4; j++) {
                int row = wr * (BM / 2) + m * 16 + lk * 4 + j;
                float v = ok ? acc[m][n][j] + bv : 0.0f;
                ldsC[row * LDC + cc] = f2b(v);
            }
    }
    __syncthreads();
    constexpr int CH = (BM * BN) / 2048;
    #pragma unroll
    for (int c = 0; c < CH; c++) {
        int o = tid + c * 256;
        int row = o / (BN / 8), col = (o % (BN / 8)) * 8;
        int gr = r0 + row;
        if (gr < M)
            *(short8*)(C + (size_t)gr * ldc + c0 + col) = *(short8*)(ldsC + row * LDC + col);
    }
}

// ---------------- fused GCN aggregate + combine (CSR gather, bf16) ----------------
template<int VEC> struct BV;
template<> struct BV<1> { using T = unsigned short; };
template<> struct BV<2> { using T = u16x2; };
template<> struct BV<4> { using T = u16x4; };

template<int VEC, bool OUTF32>
__global__ __launch_bounds__(256) void gather_k(
    const unsigned short* __restrict__ h, const unsigned short* __restrict__ base,
    const float* __restrict__ dinv, const float* __restrict__ bias,
    const int2* __restrict__ ebn, const int* __restrict__ rowptr,
    void* __restrict__ outraw, float alpha, int dorelu, int F) {
    const int ld = 64 * VEC;
    int w = (blockIdx.x * 256 + threadIdx.x) >> 6;
    int lane = threadIdx.x & 63;
    if (w >= NN) return;
    using LT = typename BV<VEC>::T;

    float acc[VEC];
    float dn = dinv[w];
    {
        LT t = *(const LT*)(h + (size_t)w * ld + lane * VEC);
        const unsigned short* tu = (const unsigned short*)&t;
        #pragma unroll
        for (int v = 0; v < VEC; v++) acc[v] = b2f(tu[v]) * dn * dn;
    }
    int e = rowptr[w], end = rowptr[w + 1];
    // 8 gather loads in flight
    for (; e + 8 <= end; e += 8) {
        int2 q[8];
        #pragma unroll
        for (int i = 0; i < 8; i++) q[i] = ebn[e + i];
        LT t[8];
        #pragma unroll
        for (int i = 0; i < 8; i++) t[i] = *(const LT*)(h + (size_t)q[i].x * ld + lane * VEC);
        #pragma unroll
        for (int i = 0; i < 8; i++) {
            float nr = __int_as_float(q[i].y);
            const unsigned short* u = (const unsigned short*)&t[i];
            #pragma unroll
            for (int v = 0; v < VEC; v++) acc[v] += b2f(u[v]) * nr;
        }
    }
    for (; e + 2 <= end; e += 2) {
        int2 q0 = ebn[e], q1 = ebn[e + 1];
        LT t0 = *(const LT*)(h + (size_t)q0.x * ld + lane * VEC);
        LT t1 = *(const LT*)(h + (size_t)q1.x * ld + lane * VEC);
        float n0 = __int_as_float(q0.y), n1 = __int_as_float(q1.y);
        const unsigned short* u0 = (const unsigned short*)&t0;
        const unsigned short* u1 = (const unsigned short*)&t1;
        #pragma unroll
        for (int v = 0; v < VEC; v++) acc[v] += b2f(u0[v]) * n0 + b2f(u1[v]) * n1;
    }
    if (e < end) {
        int2 q0 = ebn[e];
        LT t0 = *(const LT*)(h + (size_t)q0.x * ld + lane * VEC);
        float n0 = __int_as_float(q0.y);
        const unsigned short* u0 = (const unsigned short*)&t0;
        #pragma unroll
        for (int v = 0; v < VEC; v++) acc[v] += b2f(u0[v]) * n0;
    }
    LT bt = *(const LT*)(base + (size_t)w * ld + lane * VEC);
    const unsigned short* bu = (const unsigned short*)&bt;
    #pragma unroll
    for (int v = 0; v < VEC; v++) {
        int f = lane * VEC + v;
        float a = acc[v] + ((f < F) ? bias[f] : 0.0f);
        if (dorelu) a = fmaxf(a, 0.0f);
        float res = (f < F) ? b2f(bu[v]) + alpha * a : 0.0f;
        if (OUTF32) ((float*)outraw)[(size_t)w * ld + f] = res;
        else        ((unsigned short*)outraw)[(size_t)w * ld + f] = f2b(res);
    }
}

extern "C" void kernel_launch(void* const* d_in, const int* in_sizes, int n_in,
                              void* d_out, int out_size, void* d_ws, size_t ws_size,
                              hipStream_t stream) {
    const float* x   = (const float*)d_in[0];
    const int*   ei  = (const int*)d_in[1];
    const float* W1  = (const float*)d_in[2];  const float* b1  = (const float*)d_in[3];
    const float* W2  = (const float*)d_in[4];  const float* b2  = (const float*)d_in[5];
    const float* W3  = (const float*)d_in[6];  const float* b3  = (const float*)d_in[7];
    const float* Wg1 = (const float*)d_in[8];  const float* bg1 = (const float*)d_in[9];
    const float* Wg2 = (const float*)d_in[10]; const float* bg2 = (const float*)d_in[11];
    const float* Wg3 = (const float*)d_in[12]; const float* bg3 = (const float*)d_in[13];
    const float* Wg4 = (const float*)d_in[14]; const float* bg4 = (const float*)d_in[15];
    const float* Wg5 = (const float*)d_in[16]; const float* bg5 = (const float*)d_in[17];
    const float* Wg6 = (const float*)d_in[18]; const float* bg6 = (const float*)d_in[19];
    const int* srcv = ei;
    const int* dstv = ei + NE;

    float* dinv = (float*)d_ws;                         // 51200 f32
    unsigned short* hA = (unsigned short*)(dinv + 51200);   // NN x 256 bf16
    unsigned short* hB = hA + (size_t)NN * 256;
    unsigned short* hC = hB + (size_t)NN * 256;
    unsigned short* W1t  = hC + (size_t)NN * 256;  // 256x512
    unsigned short* Wg1t = W1t  + 256 * 512;       // 256x256
    unsigned short* W2t  = Wg1t + 256 * 256;       // 64x256
    unsigned short* Wg2t = W2t  + 64 * 256;        // 64x64
    unsigned short* W3t  = Wg2t + 64 * 64;         // 128x64
    unsigned short* Wg3t = W3t  + 128 * 64;        // 128x128
    unsigned short* Wg4t = Wg3t + 128 * 128;
    unsigned short* Wg5t = Wg4t + 128 * 128;
    unsigned short* Wg6t = Wg5t + 128 * 128;
    int* indeg  = (int*)(Wg6t + 128 * 128);
    int* cursor = indeg + 51200;
    int* tmp    = cursor + 51200;
    int* rowptr = tmp + 51200;                     // 51264
    int* bsum   = rowptr + 51264;
    int* boff   = bsum + 256;
    int2* ebn   = (int2*)(boff + 256);             // 400000 x 8B

    // CSR + dinv
    zero2_k<<<NBLK, 256, 0, stream>>>(indeg, cursor);
    count_k<<<(NE + 255) / 256, 256, 0, stream>>>(dstv, indeg);
    scan1_k<<<NBLK, 256, 0, stream>>>(indeg, tmp, bsum);
    scan2_k<<<1, 256, 0, stream>>>(bsum, boff);
    scan3_k<<<NBLK, 256, 0, stream>>>(tmp, indeg, boff, rowptr, dinv);
    fill_k<<<(NE + 255) / 256, 256, 0, stream>>>(srcv, dstv, dinv, rowptr, cursor, ebn);

    // weights: one merged cast+transpose launch
    {
        WSegs s;
        const float* Ws[9] = {W1, Wg1, W2, Wg2, W3, Wg3, Wg4, Wg5, Wg6};
        unsigned short* Wts[9] = {W1t, Wg1t, W2t, Wg2t, W3t, Wg3t, Wg4t, Wg5t, Wg6t};
        int Ks[9]  = {512, 256, 256, 62, 62, 128, 128, 128, 128};
        int Ns[9]  = {256, 256, 62, 62, 128, 128, 128, 128, 128};
        int Kps[9] = {512, 256, 256, 64, 64, 128, 128, 128, 128};
        int Nps[9] = {256, 256, 64, 64, 128, 128, 128, 128, 128};
        int c = 0;
        for (int g = 0; g < 9; g++) {
            s.W[g] = Ws[g]; s.Wt[g] = Wts[g];
            s.K[g] = Ks[g]; s.N[g] = Ns[g]; s.Kp[g] = Kps[g];
            s.c0[g] = c;
            c += (Kps[g] * Nps[g]) / 256;
        }
        s.c0[9] = c;
        wcast_all_k<<<c, 256, 0, stream>>>(s);
    }

    const int GX = (NN + 63) / 64;          // 782
    const int GG = (NN * 64 + 255) / 256;   // one wave per node

    // L1: x1l -> hA ; h -> hB ; x1 -> hC   (ld 256)
    gemm_mfma_k<true, 64, 128><<<dim3(GX, 2), 256, 0, stream>>>(x, W1t, b1, hA, NN, 512, 512, 256, 256);
    gemm_mfma_k<false, 64, 128><<<dim3(GX, 2), 256, 0, stream>>>(hA, Wg1t, nullptr, hB, NN, 256, 256, 256, 256);
    gather_k<4, false><<<GG, 256, 0, stream>>>(hB, hA, dinv, bg1, ebn, rowptr, hC, 1.0f, 1, 256);
    // L2: x2l -> hA ; h -> hB ; x2 -> hC   (ld 64)
    gemm_mfma_k<false, 64, 64><<<dim3(GX, 1), 256, 0, stream>>>(hC, W2t, b2, hA, NN, 256, 256, 62, 64);
    gemm_mfma_k<false, 64, 64><<<dim3(GX, 1), 256, 0, stream>>>(hA, Wg2t, nullptr, hB, NN, 64, 64, 62, 64);
    gather_k<1, false><<<GG, 256, 0, stream>>>(hB, hA, dinv, bg2, ebn, rowptr, hC, 1.0f, 1, 62);
    // L3: x3l -> hA ; h -> hB ; x3 -> hC   (ld 128)
    gemm_mfma_k<false, 64, 128><<<dim3(GX, 1), 256, 0, stream>>>(hC, W3t, b3, hA, NN, 64, 64, 128, 128);
    gemm_mfma_k<false, 64, 128><<<dim3(GX, 1), 256, 0, stream>>>(hA, Wg3t, nullptr, hB, NN, 128, 128, 128, 128);
    gather_k<2, false><<<GG, 256, 0, stream>>>(hB, hA, dinv, bg3, ebn, rowptr, hC, 0.5f, 1, 128);
    // L4: h -> hA ; x4 -> hB
    gemm_mfma_k<false, 64, 128><<<dim3(GX, 1), 256, 0, stream>>>(hC, Wg4t, nullptr, hA, NN, 128, 128, 128, 128);
    gather_k<2, false><<<GG, 256, 0, stream>>>(hA, hC, dinv, bg4, ebn, rowptr, hB, 0.5f, 1, 128);
    // L5: h -> hA ; x5 -> hC
    gemm_mfma_k<false, 64, 128><<<dim3(GX, 1), 256, 0, stream>>>(hB, Wg5t, nullptr, hA, NN, 128, 128, 128, 128);
    gather_k<2, false><<<GG, 256, 0, stream>>>(hA, hB, dinv, bg5, ebn, rowptr, hC, 0.25f, 1, 128);
    // L6: h -> hA ; x6 -> d_out (fp32)
    gemm_mfma_k<false, 64, 128><<<dim3(GX, 1), 256, 0, stream>>>(hC, Wg6t, nullptr, hA, NN, 128, 128, 128, 128);
    gather_k<2, true><<<GG, 256, 0, stream>>>(hA, hC, dinv, bg6, ebn, rowptr, d_out, 0.25f, 0, 128);
}